// Round 1
// baseline (532.973 us; speedup 1.0000x reference)
//
#include <hip/hip_runtime.h>
#include <stdint.h>

typedef unsigned short u16;
typedef __attribute__((ext_vector_type(8))) short short8;   // 8 x bf16 MFMA operand
typedef __attribute__((ext_vector_type(4))) float f32x4;    // MFMA accumulator
typedef __attribute__((ext_vector_type(4))) uint32_t u32x4;

#define KEXP   8
#define LATENT 256
#define CONDD  1024
#define HID    128
#define EIN    1281
#define EINP   1344   // 21*64, zero padded
#define NCH    21
#define NTOT   1024   // KEXP*HID
#define BROWS  32768

__device__ __forceinline__ u16 f2bf(float x) {              // RNE fp32->bf16
  uint32_t v = __float_as_uint(x);
  v += 0x7fffu + ((v >> 16) & 1u);
  return (u16)(v >> 16);
}

__device__ __forceinline__ void async16(const void* g, void* l) {
  __builtin_amdgcn_global_load_lds(
      (const __attribute__((address_space(1))) void*)g,
      (__attribute__((address_space(3))) void*)l, 16, 0, 0);
}

__device__ __forceinline__ float silu(float x) { return x / (1.f + __expf(-x)); }

// ---------------------------------------------------------------------------
// conv_w: coalesced 32x32 LDS-tiled transpose -> bf16. (unchanged)
// W1t[k][h][d]      (d padded to 1344)   from W1[k][d][h]
// W2t[k][g][h]                           from W2[k][h][g]
// W3t2[l][k*128+g]  (dense 256 x 1024)   from W3[k][g][l]
// ---------------------------------------------------------------------------
#define W1_TILES (KEXP * 42 * 4)    // 1344
#define W2_TILES (KEXP * 4 * 4)     // 128
#define W3_TILES (KEXP * 4 * 8)     // 256

__global__ void conv_w(const float* __restrict__ W1, const float* __restrict__ W2,
                       const float* __restrict__ W3,
                       u16* __restrict__ W1t, u16* __restrict__ W2t, u16* __restrict__ W3t2) {
  __shared__ float t[32][33];
  const int bid = blockIdx.x;
  const int tx = threadIdx.x & 31, ty = threadIdx.x >> 5;   // 32 x 8
  if (bid < W1_TILES) {
    int k = bid / 168, r = bid % 168;
    int d0 = (r / 4) * 32, h0 = (r % 4) * 32;
    const float* src = W1 + (size_t)k * EIN * HID;
    #pragma unroll
    for (int s = 0; s < 4; ++s) {
      int d = d0 + ty + s * 8;
      t[ty + s * 8][tx] = (d < EIN) ? src[(size_t)d * HID + h0 + tx] : 0.f;
    }
    __syncthreads();
    u16* dst = W1t + (size_t)k * HID * EINP;
    #pragma unroll
    for (int s = 0; s < 4; ++s)
      dst[(size_t)(h0 + ty + s * 8) * EINP + d0 + tx] = f2bf(t[tx][ty + s * 8]);
  } else if (bid < W1_TILES + W2_TILES) {
    int j = bid - W1_TILES;
    int k = j / 16, r = j % 16;
    int d0 = (r / 4) * 32, h0 = (r % 4) * 32;
    const float* src = W2 + (size_t)k * HID * HID;
    #pragma unroll
    for (int s = 0; s < 4; ++s)
      t[ty + s * 8][tx] = src[(size_t)(d0 + ty + s * 8) * HID + h0 + tx];
    __syncthreads();
    u16* dst = W2t + (size_t)k * HID * HID;
    #pragma unroll
    for (int s = 0; s < 4; ++s)
      dst[(size_t)(h0 + ty + s * 8) * HID + d0 + tx] = f2bf(t[tx][ty + s * 8]);
  } else {
    int j = bid - W1_TILES - W2_TILES;
    int k = j / 32, r = j % 32;
    int d0 = (r / 8) * 32, h0 = (r % 8) * 32;   // d=g (128), h=l (256)
    const float* src = W3 + (size_t)k * HID * LATENT;
    #pragma unroll
    for (int s = 0; s < 4; ++s)
      t[ty + s * 8][tx] = src[(size_t)(d0 + ty + s * 8) * LATENT + h0 + tx];
    __syncthreads();
    #pragma unroll
    for (int s = 0; s < 4; ++s)
      W3t2[(size_t)(h0 + ty + s * 8) * NTOT + k * HID + d0 + tx] = f2bf(t[tx][ty + s * 8]);
  }
}

// ---------------------------------------------------------------------------
// x_conv: Xbf[b][1344] = bf16(concat(u, cond, tau, 0-pad)). Streaming,
// 16B stores, one u32x4 per thread. 32768*168 groups / 256 = 21504 blocks.
// ---------------------------------------------------------------------------
#define XGRP (BROWS * 168)

__global__ __launch_bounds__(256)
void x_conv(const float* __restrict__ cond, const float* __restrict__ uu,
            const float* __restrict__ tau, u16* __restrict__ Xbf) {
  int g = blockIdx.x * 256 + threadIdx.x;
  if (g >= XGRP) return;
  int row = g / 168;
  int c8  = g - row * 168;
  float f0 = 0.f, f1 = 0.f, f2 = 0.f, f3 = 0.f, f4 = 0.f, f5 = 0.f, f6 = 0.f, f7 = 0.f;
  if (c8 < 32) {
    const float4* p = (const float4*)(uu + (size_t)row * LATENT + c8 * 8);
    float4 a = p[0], b = p[1];
    f0 = a.x; f1 = a.y; f2 = a.z; f3 = a.w; f4 = b.x; f5 = b.y; f6 = b.z; f7 = b.w;
  } else if (c8 < 160) {
    const float4* p = (const float4*)(cond + (size_t)row * CONDD + (c8 - 32) * 8);
    float4 a = p[0], b = p[1];
    f0 = a.x; f1 = a.y; f2 = a.z; f3 = a.w; f4 = b.x; f5 = b.y; f6 = b.z; f7 = b.w;
  } else if (c8 == 160) {
    f0 = tau[row];                       // col 1280; 1281.. zero
  }
  u32x4 pk;
  pk[0] = (uint32_t)f2bf(f0) | ((uint32_t)f2bf(f1) << 16);
  pk[1] = (uint32_t)f2bf(f2) | ((uint32_t)f2bf(f3) << 16);
  pk[2] = (uint32_t)f2bf(f4) | ((uint32_t)f2bf(f5) << 16);
  pk[3] = (uint32_t)f2bf(f6) | ((uint32_t)f2bf(f7) << 16);
  *(u32x4*)(Xbf + (size_t)row * EINP + c8 * 8) = pk;
}

// ---------------------------------------------------------------------------
// h1_fused: H[:, e*128:] = p[:,e] * silu( silu(X@W1t[e]+b1) @ W2t[e] + b2 ).
// Main loop: pure async16 staging (zero VALU), 128x128 tile, BK=64, 21 chunks.
// GEMM2 fused in-block (the 128x128 H1 tile is complete per block).
// LDS 48.5 KB -> 3 blocks/CU.
// ---------------------------------------------------------------------------
__global__ __launch_bounds__(256, 3)
void h1_fused(const u16* __restrict__ Xbf, const u16* __restrict__ W1t,
              const float* __restrict__ b1, const u16* __restrict__ W2t,
              const float* __restrict__ b2, const float* __restrict__ p_hat,
              u16* __restrict__ H) {
  __shared__ struct {
    union {
      struct { u16 As[128 * 64]; u16 Bs[128 * 64]; } s;   // 32 KB main staging
      u16 As2[128 * 128];                                 // 32 KB H1 bf16 tile
      u16 Cs[128 * 72];                                   // 18 KB epilogue
    } u;
    u16 Bs2[128 * 64];                                    // 16 KB W2 chunk
    float Ps[128];
  } sm;

  const int tid  = threadIdx.x;
  const int wave = tid >> 6;
  const int lane = tid & 63;
  const int q    = lane >> 4;
  const int ln   = lane & 15;
  const int wm   = wave >> 1, wn = wave & 1;
  const int bid  = blockIdx.x;
  const int mt   = ((bid >> 6) << 3) | (bid & 7);   // 0..255, same-XCD siblings
  const int e    = (bid >> 3) & 7;                  // expert
  const int m0   = mt * 128;
  const u16* w1k = W1t + (size_t)e * HID * EINP;
  const u16* xtb = Xbf + (size_t)m0 * EINP;

  if (tid < 128) sm.Ps[tid] = p_hat[(size_t)(m0 + tid) * KEXP + e];

  const f32x4 fz = {0.f, 0.f, 0.f, 0.f};
  f32x4 acc[4][4];
  #pragma unroll
  for (int m = 0; m < 4; ++m)
    #pragma unroll
    for (int n = 0; n < 4; ++n) acc[m][n] = fz;

  const int rloc = lane >> 3;
  const int gsw  = lane & 7;
  const int gsrc = gsw ^ rloc;      // pre-swizzled global source, linear LDS dest

  // ---------------- GEMM1: X @ W1t, K = 1344 ----------------
  #pragma unroll 1
  for (int ic = 0; ic < NCH; ++ic) {
    const int d0 = ic * 64;
    #pragma unroll
    for (int i = 0; i < 4; ++i) {
      int rbase = (wave * 4 + i) * 8;
      async16(xtb + (size_t)(rbase + rloc) * EINP + d0 + gsrc * 8, &sm.u.s.As[rbase * 64]);
      async16(w1k + (size_t)(rbase + rloc) * EINP + d0 + gsrc * 8, &sm.u.s.Bs[rbase * 64]);
    }
    __syncthreads();
    #pragma unroll
    for (int ks = 0; ks < 2; ++ks) {
      short8 a[4], b[4];
      #pragma unroll
      for (int m = 0; m < 4; ++m) {
        int r = wm * 64 + m * 16 + ln;
        int g = (ks * 4 + q) ^ (r & 7);
        a[m] = *(const short8*)(&sm.u.s.As[r * 64 + g * 8]);
      }
      #pragma unroll
      for (int n = 0; n < 4; ++n) {
        int c = wn * 64 + n * 16 + ln;
        int g = (ks * 4 + q) ^ (c & 7);
        b[n] = *(const short8*)(&sm.u.s.Bs[c * 64 + g * 8]);
      }
      #pragma unroll
      for (int m = 0; m < 4; ++m)
        #pragma unroll
        for (int n = 0; n < 4; ++n)
          acc[m][n] = __builtin_amdgcn_mfma_f32_16x16x32_bf16(a[m], b[n], acc[m][n], 0, 0, 0);
    }
    __syncthreads();
  }

  // ---------------- fused GEMM2: silu(acc+b1) @ W2t[e], K = 128 ----------------
  // Write the full 128x128 H1 tile as bf16 into As2, XOR-swizzled:
  // element (row,h) at As2[row*128 + ((h>>3)^(row&7))*8 + (h&7)]
  // ((h>>3) is 4-bit; XOR with 3-bit row&7 keeps bit 3 -> bijective.)
  #pragma unroll
  for (int n = 0; n < 4; ++n) {
    int cl = wn * 64 + n * 16 + ln;            // h = 0..127
    float bv = b1[e * HID + cl];
    #pragma unroll
    for (int m = 0; m < 4; ++m)
      #pragma unroll
      for (int r = 0; r < 4; ++r) {
        int row = wm * 64 + m * 16 + q * 4 + r;
        sm.u.As2[row * 128 + (((cl >> 3) ^ (row & 7)) << 3) + (cl & 7)] =
            f2bf(silu(acc[m][n][r] + bv));
      }
  }

  f32x4 acc2[4][4];
  #pragma unroll
  for (int m = 0; m < 4; ++m)
    #pragma unroll
    for (int n = 0; n < 4; ++n) acc2[m][n] = fz;

  const u16* w2k = W2t + (size_t)e * HID * HID;

  #pragma unroll 1
  for (int kc = 0; kc < 2; ++kc) {
    #pragma unroll
    for (int i = 0; i < 4; ++i) {
      int rbase = (wave * 4 + i) * 8;
      async16(w2k + (size_t)(rbase + rloc) * HID + kc * 64 + gsrc * 8, &sm.Bs2[rbase * 64]);
    }
    __syncthreads();   // As2 writes (lgkm) + Bs2 async16 (vmcnt) both drained
    #pragma unroll
    for (int ks = 0; ks < 2; ++ks) {
      short8 a[4], b[4];
      #pragma unroll
      for (int m = 0; m < 4; ++m) {
        int r = wm * 64 + m * 16 + ln;
        int G = kc * 8 + ks * 4 + q;           // 4-bit h-group
        int g = (G & 8) | ((G ^ (r & 7)) & 7);
        a[m] = *(const short8*)(&sm.u.As2[r * 128 + g * 8]);
      }
      #pragma unroll
      for (int n = 0; n < 4; ++n) {
        int c = wn * 64 + n * 16 + ln;
        int g = (ks * 4 + q) ^ (c & 7);
        b[n] = *(const short8*)(&sm.Bs2[c * 64 + g * 8]);
      }
      #pragma unroll
      for (int m = 0; m < 4; ++m)
        #pragma unroll
        for (int n = 0; n < 4; ++n)
          acc2[m][n] = __builtin_amdgcn_mfma_f32_16x16x32_bf16(a[m], b[n], acc2[m][n], 0, 0, 0);
    }
    __syncthreads();
  }

  // ---------------- epilogue: p * silu(acc2 + b2) -> bf16 H, coalesced ----------------
  u16* hb = H + (size_t)m0 * NTOT + e * HID;
  #pragma unroll 1
  for (int hf = 0; hf < 2; ++hf) {
    if (wn == hf) {
      #pragma unroll
      for (int n = 0; n < 4; ++n) {
        int cl = n * 16 + ln;
        float bv = b2[e * HID + hf * 64 + cl];
        #pragma unroll
        for (int m = 0; m < 4; ++m)
          #pragma unroll
          for (int r = 0; r < 4; ++r) {
            int row = wm * 64 + m * 16 + q * 4 + r;
            sm.u.Cs[row * 72 + cl] = f2bf(sm.Ps[row] * silu(acc2[m][n][r] + bv));
          }
      }
    }
    __syncthreads();
    #pragma unroll
    for (int i = 0; i < 4; ++i) {
      int lin = tid + i * 256;
      int row = lin >> 3;
      int grp = lin & 7;
      *(u32x4*)(hb + (size_t)row * NTOT + hf * 64 + grp * 8) =
          *(const u32x4*)(&sm.u.Cs[row * 72 + grp * 8]);
    }
    __syncthreads();
  }
}

// ---------------------------------------------------------------------------
// FALLBACK PATH (only if ws_size is too small for Xbf): previous-session
// h1_gemm + h2_gemm, verbatim.
// ---------------------------------------------------------------------------
__global__ __launch_bounds__(256, 4)
void h1_gemm(const float* __restrict__ cond, const float* __restrict__ uu,
             const float* __restrict__ tau, const u16* __restrict__ W1t,
             const float* __restrict__ b1, u16* __restrict__ H1) {
  __shared__ union {
    struct { u16 As[128 * 64]; u16 Bs[128 * 64]; } s;
    u16 Cs[128 * 72];
  } sm;

  const int tid  = threadIdx.x;
  const int wave = tid >> 6;
  const int lane = tid & 63;
  const int q    = lane >> 4;
  const int ln   = lane & 15;
  const int wm   = wave >> 1, wn = wave & 1;
  const int bid  = blockIdx.x;
  const int mt   = ((bid >> 6) << 3) | (bid & 7);
  const int e    = (bid >> 3) & 7;
  const int m0   = mt * 128, n0 = e * 128;
  const u16* w1k = W1t + (size_t)e * HID * EINP;

  const f32x4 fz = {0.f, 0.f, 0.f, 0.f};
  f32x4 acc[4][4];
  #pragma unroll
  for (int m = 0; m < 4; ++m)
    #pragma unroll
    for (int n = 0; n < 4; ++n) acc[m][n] = fz;

  #pragma unroll 1
  for (int ic = 0; ic < NCH; ++ic) {
    const int d0 = ic * 64;
    #pragma unroll
    for (int i = 0; i < 4; ++i) {
      int lin  = tid + i * 256;
      int row  = lin >> 3;
      int gsw  = lin & 7;
      int gsrc = gsw ^ (row & 7);
      int gr   = m0 + row;
      float f0, f1, f2, f3, f4, f5, f6, f7;
      if (d0 < 256) {
        const float4* p = (const float4*)(uu + (size_t)gr * LATENT + d0 + gsrc * 8);
        float4 A = p[0], Bv = p[1];
        f0 = A.x; f1 = A.y; f2 = A.z; f3 = A.w; f4 = Bv.x; f5 = Bv.y; f6 = Bv.z; f7 = Bv.w;
      } else if (d0 < 1280) {
        const float4* p = (const float4*)(cond + (size_t)gr * CONDD + (d0 - 256) + gsrc * 8);
        float4 A = p[0], Bv = p[1];
        f0 = A.x; f1 = A.y; f2 = A.z; f3 = A.w; f4 = Bv.x; f5 = Bv.y; f6 = Bv.z; f7 = Bv.w;
      } else {
        float tv = tau[gr];
        f0 = (gsrc == 0) ? tv : 0.f;
        f1 = f2 = f3 = f4 = f5 = f6 = f7 = 0.f;
      }
      u32x4 pk;
      pk[0] = (uint32_t)f2bf(f0) | ((uint32_t)f2bf(f1) << 16);
      pk[1] = (uint32_t)f2bf(f2) | ((uint32_t)f2bf(f3) << 16);
      pk[2] = (uint32_t)f2bf(f4) | ((uint32_t)f2bf(f5) << 16);
      pk[3] = (uint32_t)f2bf(f6) | ((uint32_t)f2bf(f7) << 16);
      *(u32x4*)(&sm.s.As[row * 64 + gsw * 8]) = pk;
    }
    {
      int rloc = lane >> 3;
      int gsw  = lane & 7;
      int gsrc = gsw ^ rloc;
      #pragma unroll
      for (int i = 0; i < 4; ++i) {
        int rbase = (wave * 4 + i) * 8;
        async16(w1k + (size_t)(rbase + rloc) * EINP + d0 + gsrc * 8,
                &sm.s.Bs[rbase * 64]);
      }
    }
    __syncthreads();
    #pragma unroll
    for (int ks = 0; ks < 2; ++ks) {
      short8 a[4], b[4];
      #pragma unroll
      for (int m = 0; m < 4; ++m) {
        int r = wm * 64 + m * 16 + ln;
        int g = (ks * 4 + q) ^ (r & 7);
        a[m] = *(const short8*)(&sm.s.As[r * 64 + g * 8]);
      }
      #pragma unroll
      for (int n = 0; n < 4; ++n) {
        int c = wn * 64 + n * 16 + ln;
        int g = (ks * 4 + q) ^ (c & 7);
        b[n] = *(const short8*)(&sm.s.Bs[c * 64 + g * 8]);
      }
      #pragma unroll
      for (int m = 0; m < 4; ++m)
        #pragma unroll
        for (int n = 0; n < 4; ++n)
          acc[m][n] = __builtin_amdgcn_mfma_f32_16x16x32_bf16(a[m], b[n], acc[m][n], 0, 0, 0);
    }
    __syncthreads();
  }

  #pragma unroll 1
  for (int hf = 0; hf < 2; ++hf) {
    if (wn == hf) {
      #pragma unroll
      for (int n = 0; n < 4; ++n) {
        int cl = n * 16 + ln;
        float bv = b1[n0 + hf * 64 + cl];
        #pragma unroll
        for (int m = 0; m < 4; ++m)
          #pragma unroll
          for (int r = 0; r < 4; ++r)
            sm.Cs[(wm * 64 + m * 16 + q * 4 + r) * 72 + cl] = f2bf(silu(acc[m][n][r] + bv));
      }
    }
    __syncthreads();
    #pragma unroll
    for (int i = 0; i < 4; ++i) {
      int lin = tid + i * 256;
      int row = lin >> 3;
      int grp = lin & 7;
      *(u32x4*)(H1 + (size_t)(m0 + row) * NTOT + n0 + hf * 64 + grp * 8) =
          *(const u32x4*)(&sm.Cs[row * 72 + grp * 8]);
    }
    __syncthreads();
  }
}

__global__ __launch_bounds__(256, 4)
void h2_gemm(u16* __restrict__ H, const float* __restrict__ p_hat,
             const u16* __restrict__ W2t, const float* __restrict__ b2) {
  __shared__ struct {
    union { struct { u16 As[128 * 64]; u16 Bs[128 * 64]; } s; u16 Cs[128 * 72]; } u;
    float Ps[128];
  } sm;

  const int tid  = threadIdx.x;
  const int wave = tid >> 6;
  const int lane = tid & 63;
  const int q    = lane >> 4;
  const int ln   = lane & 15;
  const int wm   = wave >> 1, wn = wave & 1;
  const int mt   = blockIdx.x >> 3;
  const int e    = blockIdx.x & 7;
  const int row0 = mt * 128;

  if (tid < 128) sm.Ps[tid] = p_hat[(size_t)(row0 + tid) * KEXP + e];

  const u16* w2k = W2t + (size_t)e * HID * HID;
  u16* hb = H + (size_t)row0 * NTOT + e * HID;

  const f32x4 fz = {0.f, 0.f, 0.f, 0.f};
  f32x4 acc[4][4];
  #pragma unroll
  for (int m = 0; m < 4; ++m)
    #pragma unroll
    for (int n = 0; n < 4; ++n) acc[m][n] = fz;

  const int rloc = lane >> 3;
  const int gsw  = lane & 7;
  const int gsrc = gsw ^ rloc;

  #pragma unroll 1
  for (int kc = 0; kc < 2; ++kc) {
    #pragma unroll
    for (int i = 0; i < 4; ++i) {
      int rbase = (wave * 4 + i) * 8;
      async16(hb + (size_t)(rbase + rloc) * NTOT + kc * 64 + gsrc * 8,
              &sm.u.s.As[rbase * 64]);
      async16(w2k + (size_t)(rbase + rloc) * HID + kc * 64 + gsrc * 8,
              &sm.u.s.Bs[rbase * 64]);
    }
    __syncthreads();
    #pragma unroll
    for (int ks = 0; ks < 2; ++ks) {
      short8 a[4], b[4];
      #pragma unroll
      for (int m = 0; m < 4; ++m) {
        int r = wm * 64 + m * 16 + ln;
        int g = (ks * 4 + q) ^ (r & 7);
        a[m] = *(const short8*)(&sm.u.s.As[r * 64 + g * 8]);
      }
      #pragma unroll
      for (int n = 0; n < 4; ++n) {
        int c = wn * 64 + n * 16 + ln;
        int g = (ks * 4 + q) ^ (c & 7);
        b[n] = *(const short8*)(&sm.u.s.Bs[c * 64 + g * 8]);
      }
      #pragma unroll
      for (int m = 0; m < 4; ++m)
        #pragma unroll
        for (int n = 0; n < 4; ++n)
          acc[m][n] = __builtin_amdgcn_mfma_f32_16x16x32_bf16(a[m], b[n], acc[m][n], 0, 0, 0);
    }
    __syncthreads();
  }

  #pragma unroll 1
  for (int hf = 0; hf < 2; ++hf) {
    if (wn == hf) {
      #pragma unroll
      for (int n = 0; n < 4; ++n) {
        int cl = n * 16 + ln;
        float bv = b2[e * HID + hf * 64 + cl];
        #pragma unroll
        for (int m = 0; m < 4; ++m)
          #pragma unroll
          for (int r = 0; r < 4; ++r) {
            int row = wm * 64 + m * 16 + q * 4 + r;
            sm.u.Cs[row * 72 + cl] = f2bf(sm.Ps[row] * silu(acc[m][n][r] + bv));
          }
      }
    }
    __syncthreads();
    #pragma unroll
    for (int i = 0; i < 4; ++i) {
      int lin = tid + i * 256;
      int row = lin >> 3;
      int grp = lin & 7;
      *(u32x4*)(hb + (size_t)row * NTOT + hf * 64 + grp * 8) =
          *(const u32x4*)(&sm.u.Cs[row * 72 + grp * 8]);
    }
    __syncthreads();
  }
}

// ---------------------------------------------------------------------------
// Kernel C: out = Hg @ W3t2^T + (p @ b3). (unchanged)
// ---------------------------------------------------------------------------
__global__ __launch_bounds__(256, 4)
void out_gemm(const u16* __restrict__ H, const float* __restrict__ p_hat,
              const u16* __restrict__ W3t2, const float* __restrict__ b3,
              float* __restrict__ out) {
  __shared__ struct {
    u16 As[64 * 64];      // 8 KB
    u16 Bs[128 * 64];     // 16 KB
    float Ps[64 * 8];     // 2 KB
    float B3s[128 * 8];   // 4 KB
  } sm;

  const int tid  = threadIdx.x;
  const int wave = tid >> 6;
  const int lane = tid & 63;
  const int q    = lane >> 4;
  const int ln   = lane & 15;
  const int bid  = blockIdx.x;
  const int mt   = ((bid >> 4) << 3) | (bid & 7);   // 0..511
  const int bn   = (bid >> 3) & 1;
  const int m0   = mt * 64, n0 = bn * 128;

  if (tid < 128) {
    int row = tid >> 1, h = tid & 1;
    *(float4*)(&sm.Ps[row * 8 + h * 4]) = *(const float4*)(p_hat + (size_t)(m0 + row) * KEXP + h * 4);
  }
  #pragma unroll
  for (int i = 0; i < 4; ++i) {
    int k = i * 2 + (tid >> 7);
    int c = tid & 127;
    sm.B3s[c * 8 + k] = b3[k * LATENT + n0 + c];
  }

  const f32x4 fz = {0.f, 0.f, 0.f, 0.f};
  f32x4 acc[4][2];
  #pragma unroll
  for (int m = 0; m < 4; ++m) { acc[m][0] = fz; acc[m][1] = fz; }

  const int rloc = lane >> 3;
  const int gsw  = lane & 7;
  const int gsrc = gsw ^ rloc;

  #pragma unroll 1
  for (int kc = 0; kc < 16; ++kc) {
    #pragma unroll
    for (int i = 0; i < 2; ++i) {
      int rbase = (wave * 2 + i) * 8;
      async16(H + (size_t)(m0 + rbase + rloc) * NTOT + kc * 64 + gsrc * 8,
              &sm.As[rbase * 64]);
    }
    #pragma unroll
    for (int i = 0; i < 4; ++i) {
      int rbase = (wave * 4 + i) * 8;
      async16(W3t2 + (size_t)(n0 + rbase + rloc) * NTOT + kc * 64 + gsrc * 8,
              &sm.Bs[rbase * 64]);
    }
    __syncthreads();
    #pragma unroll
    for (int ks = 0; ks < 2; ++ks) {
      short8 a[4], b[2];
      #pragma unroll
      for (int m = 0; m < 4; ++m) {
        int r = m * 16 + ln;
        int g = (ks * 4 + q) ^ (r & 7);
        a[m] = *(const short8*)(&sm.As[r * 64 + g * 8]);
      }
      #pragma unroll
      for (int n = 0; n < 2; ++n) {
        int c = wave * 32 + n * 16 + ln;
        int g = (ks * 4 + q) ^ (c & 7);
        b[n] = *(const short8*)(&sm.Bs[c * 64 + g * 8]);
      }
      #pragma unroll
      for (int m = 0; m < 4; ++m)
        #pragma unroll
        for (int n = 0; n < 2; ++n)
          acc[m][n] = __builtin_amdgcn_mfma_f32_16x16x32_bf16(a[m], b[n], acc[m][n], 0, 0, 0);
    }
    __syncthreads();
  }

  #pragma unroll
  for (int n = 0; n < 2; ++n) {
    int col = wave * 32 + n * 16 + ln;
    float4 c0 = *(const float4*)(&sm.B3s[col * 8]);
    float4 c1 = *(const float4*)(&sm.B3s[col * 8 + 4]);
    #pragma unroll
    for (int m = 0; m < 4; ++m)
      #pragma unroll
      for (int r = 0; r < 4; ++r) {
        int row = m * 16 + q * 4 + r;
        float4 p0 = *(const float4*)(&sm.Ps[row * 8]);
        float4 p1 = *(const float4*)(&sm.Ps[row * 8 + 4]);
        float v = acc[m][n][r]
                + p0.x * c0.x + p0.y * c0.y + p0.z * c0.z + p0.w * c0.w
                + p1.x * c1.x + p1.y * c1.y + p1.z * c1.z + p1.w * c1.w;
        out[(size_t)(m0 + row) * LATENT + n0 + col] = v;
      }
  }
}

extern "C" void kernel_launch(void* const* d_in, const int* in_sizes, int n_in,
                              void* d_out, int out_size, void* d_ws, size_t ws_size,
                              hipStream_t stream) {
  const float* cond  = (const float*)d_in[0];
  const float* u     = (const float*)d_in[1];
  const float* tau   = (const float*)d_in[2];
  const float* p_hat = (const float*)d_in[3];
  const float* W1    = (const float*)d_in[4];
  const float* b1    = (const float*)d_in[5];
  const float* W2    = (const float*)d_in[6];
  const float* b2    = (const float*)d_in[7];
  const float* W3    = (const float*)d_in[8];
  const float* b3    = (const float*)d_in[9];
  float* out = (float*)d_out;

  const size_t N1 = (size_t)KEXP * HID * EINP;    // 1,376,256
  const size_t N2 = (size_t)KEXP * HID * HID;     //   131,072
  const size_t N3 = (size_t)LATENT * NTOT;        //   262,144
  const size_t NH = (size_t)BROWS * NTOT;         // 33,554,432
  const size_t NX = (size_t)BROWS * EINP;         // 44,040,192 (bf16 X)

  u16* W1t  = (u16*)d_ws;
  u16* W2t  = W1t + N1;
  u16* W3t2 = W2t + N2;
  u16* H    = W3t2 + N3;

  if (ws_size >= (N1 + N2 + N3 + NH + NX) * sizeof(u16)) {
    // ---- fast path: bf16 X prepass + fused h1+h2 ----
    u16* Xbf = H + NH;
    conv_w<<<W1_TILES + W2_TILES + W3_TILES, 256, 0, stream>>>(W1, W2, W3, W1t, W2t, W3t2);
    x_conv<<<XGRP / 256, 256, 0, stream>>>(cond, u, tau, Xbf);
    h1_fused<<<2048, 256, 0, stream>>>(Xbf, W1t, b1, W2t, b2, p_hat, H);
    out_gemm<<<1024, 256, 0, stream>>>(H, p_hat, W3t2, b3, out);
  } else if (ws_size >= (N1 + N2 + N3 + NH) * sizeof(u16)) {
    // ---- fallback: previous-session path ----
    conv_w<<<W1_TILES + W2_TILES + W3_TILES, 256, 0, stream>>>(W1, W2, W3, W1t, W2t, W3t2);
    h1_gemm<<<2048, 256, 0, stream>>>(cond, u, tau, W1t, b1, H);
    h2_gemm<<<2048, 256, 0, stream>>>(H, p_hat, W2t, b2);
    out_gemm<<<1024, 256, 0, stream>>>(H, p_hat, W3t2, b3, out);
  }
}

// Round 3
// 435.687 us; speedup vs baseline: 1.2233x; 1.2233x over previous
//
#include <hip/hip_runtime.h>
#include <stdint.h>

typedef unsigned short u16;
typedef __attribute__((ext_vector_type(8))) short short8;   // 8 x bf16 MFMA operand
typedef __attribute__((ext_vector_type(4))) float f32x4;    // MFMA accumulator
typedef __attribute__((ext_vector_type(4))) uint32_t u32x4;

#define KEXP   8
#define LATENT 256
#define CONDD  1024
#define HID    128
#define EIN    1281
#define EINP   1344   // 21*64, zero padded
#define NCH    21
#define NTOT   1024   // KEXP*HID
#define BROWS  32768

__device__ __forceinline__ u16 f2bf(float x) {              // RNE fp32->bf16
  uint32_t v = __float_as_uint(x);
  v += 0x7fffu + ((v >> 16) & 1u);
  return (u16)(v >> 16);
}

__device__ __forceinline__ void async16(const void* g, void* l) {
  __builtin_amdgcn_global_load_lds(
      (const __attribute__((address_space(1))) void*)g,
      (__attribute__((address_space(3))) void*)l, 16, 0, 0);
}

__device__ __forceinline__ float silu(float x) { return x / (1.f + __expf(-x)); }

// ---------------------------------------------------------------------------
// conv_w: coalesced 32x32 LDS-tiled transpose -> bf16. (unchanged)
// ---------------------------------------------------------------------------
#define W1_TILES (KEXP * 42 * 4)    // 1344
#define W2_TILES (KEXP * 4 * 4)     // 128
#define W3_TILES (KEXP * 4 * 8)     // 256

__global__ void conv_w(const float* __restrict__ W1, const float* __restrict__ W2,
                       const float* __restrict__ W3,
                       u16* __restrict__ W1t, u16* __restrict__ W2t, u16* __restrict__ W3t2) {
  __shared__ float t[32][33];
  const int bid = blockIdx.x;
  const int tx = threadIdx.x & 31, ty = threadIdx.x >> 5;   // 32 x 8
  if (bid < W1_TILES) {
    int k = bid / 168, r = bid % 168;
    int d0 = (r / 4) * 32, h0 = (r % 4) * 32;
    const float* src = W1 + (size_t)k * EIN * HID;
    #pragma unroll
    for (int s = 0; s < 4; ++s) {
      int d = d0 + ty + s * 8;
      t[ty + s * 8][tx] = (d < EIN) ? src[(size_t)d * HID + h0 + tx] : 0.f;
    }
    __syncthreads();
    u16* dst = W1t + (size_t)k * HID * EINP;
    #pragma unroll
    for (int s = 0; s < 4; ++s)
      dst[(size_t)(h0 + ty + s * 8) * EINP + d0 + tx] = f2bf(t[tx][ty + s * 8]);
  } else if (bid < W1_TILES + W2_TILES) {
    int j = bid - W1_TILES;
    int k = j / 16, r = j % 16;
    int d0 = (r / 4) * 32, h0 = (r % 4) * 32;
    const float* src = W2 + (size_t)k * HID * HID;
    #pragma unroll
    for (int s = 0; s < 4; ++s)
      t[ty + s * 8][tx] = src[(size_t)(d0 + ty + s * 8) * HID + h0 + tx];
    __syncthreads();
    u16* dst = W2t + (size_t)k * HID * HID;
    #pragma unroll
    for (int s = 0; s < 4; ++s)
      dst[(size_t)(h0 + ty + s * 8) * HID + d0 + tx] = f2bf(t[tx][ty + s * 8]);
  } else {
    int j = bid - W1_TILES - W2_TILES;
    int k = j / 32, r = j % 32;
    int d0 = (r / 8) * 32, h0 = (r % 8) * 32;   // d=g (128), h=l (256)
    const float* src = W3 + (size_t)k * HID * LATENT;
    #pragma unroll
    for (int s = 0; s < 4; ++s)
      t[ty + s * 8][tx] = src[(size_t)(d0 + ty + s * 8) * LATENT + h0 + tx];
    __syncthreads();
    #pragma unroll
    for (int s = 0; s < 4; ++s)
      W3t2[(size_t)(h0 + ty + s * 8) * NTOT + k * HID + d0 + tx] = f2bf(t[tx][ty + s * 8]);
  }
}

// ---------------------------------------------------------------------------
// x_conv: Xbf[b][1344] = bf16(concat(u, cond, tau, 0-pad)). (unchanged)
// ---------------------------------------------------------------------------
#define XGRP (BROWS * 168)

__global__ __launch_bounds__(256)
void x_conv(const float* __restrict__ cond, const float* __restrict__ uu,
            const float* __restrict__ tau, u16* __restrict__ Xbf) {
  int g = blockIdx.x * 256 + threadIdx.x;
  if (g >= XGRP) return;
  int row = g / 168;
  int c8  = g - row * 168;
  float f0 = 0.f, f1 = 0.f, f2 = 0.f, f3 = 0.f, f4 = 0.f, f5 = 0.f, f6 = 0.f, f7 = 0.f;
  if (c8 < 32) {
    const float4* p = (const float4*)(uu + (size_t)row * LATENT + c8 * 8);
    float4 a = p[0], b = p[1];
    f0 = a.x; f1 = a.y; f2 = a.z; f3 = a.w; f4 = b.x; f5 = b.y; f6 = b.z; f7 = b.w;
  } else if (c8 < 160) {
    const float4* p = (const float4*)(cond + (size_t)row * CONDD + (c8 - 32) * 8);
    float4 a = p[0], b = p[1];
    f0 = a.x; f1 = a.y; f2 = a.z; f3 = a.w; f4 = b.x; f5 = b.y; f6 = b.z; f7 = b.w;
  } else if (c8 == 160) {
    f0 = tau[row];                       // col 1280; 1281.. zero
  }
  u32x4 pk;
  pk[0] = (uint32_t)f2bf(f0) | ((uint32_t)f2bf(f1) << 16);
  pk[1] = (uint32_t)f2bf(f2) | ((uint32_t)f2bf(f3) << 16);
  pk[2] = (uint32_t)f2bf(f4) | ((uint32_t)f2bf(f5) << 16);
  pk[3] = (uint32_t)f2bf(f6) | ((uint32_t)f2bf(f7) << 16);
  *(u32x4*)(Xbf + (size_t)row * EINP + c8 * 8) = pk;
}

// ---------------------------------------------------------------------------
// h1_fused: H[:, e*128:] = p[:,e] * silu( silu(X@W1t[e]+b1) @ W2t[e] + b2 ).
// T3/T4 pipeline: double-buffered As/Bs, stage(t+1) -> vmcnt(8) -> s_barrier
// -> MFMA(t) -> s_barrier.  Loads stay in flight across barriers.
// GEMM2: both W2 chunks prefetched up front (Bs2[2]), single barrier.
// LDS 64.5 KB -> 2 blocks/CU; setprio around MFMA.
// ---------------------------------------------------------------------------
__global__ __launch_bounds__(256, 2)
void h1_fused(const u16* __restrict__ Xbf, const u16* __restrict__ W1t,
              const float* __restrict__ b1, const u16* __restrict__ W2t,
              const float* __restrict__ b2, const float* __restrict__ p_hat,
              u16* __restrict__ H) {
  __shared__ struct {
    union {
      struct { u16 As[2][128 * 64]; u16 Bs[2][128 * 64]; } s;   // 64 KB staging
      struct { u16 As2[128 * 128]; u16 Bs2[2][128 * 64]; } g;   // 64 KB GEMM2
      u16 Cs[128 * 72];                                         // 18 KB epilogue
    } u;
    float Ps[128];
  } sm;

  const int tid  = threadIdx.x;
  const int wave = tid >> 6;
  const int lane = tid & 63;
  const int q    = lane >> 4;
  const int ln   = lane & 15;
  const int wm   = wave >> 1, wn = wave & 1;
  const int bid  = blockIdx.x;
  const int mt   = ((bid >> 6) << 3) | (bid & 7);   // 0..255, same-XCD siblings
  const int e    = (bid >> 3) & 7;                  // expert
  const int m0   = mt * 128;
  const u16* w1k = W1t + (size_t)e * HID * EINP;
  const u16* xtb = Xbf + (size_t)m0 * EINP;

  if (tid < 128) sm.Ps[tid] = p_hat[(size_t)(m0 + tid) * KEXP + e];

  const f32x4 fz = {0.f, 0.f, 0.f, 0.f};
  f32x4 acc[4][4];
  #pragma unroll
  for (int m = 0; m < 4; ++m)
    #pragma unroll
    for (int n = 0; n < 4; ++n) acc[m][n] = fz;

  const int rloc = lane >> 3;
  const int gsw  = lane & 7;
  const int gsrc = gsw ^ rloc;      // pre-swizzled global source, linear LDS dest

  // ---------------- GEMM1: X @ W1t, K = 1344, pipelined ----------------
  // prologue: stage chunk 0 into buffer 0 (8 async16 per wave)
  #pragma unroll
  for (int i = 0; i < 4; ++i) {
    int rbase = (wave * 4 + i) * 8;
    async16(xtb + (size_t)(rbase + rloc) * EINP + gsrc * 8, &sm.u.s.As[0][rbase * 64]);
    async16(w1k + (size_t)(rbase + rloc) * EINP + gsrc * 8, &sm.u.s.Bs[0][rbase * 64]);
  }

  #pragma unroll 1
  for (int ic = 0; ic < NCH; ++ic) {
    const int bf = ic & 1;
    if (ic + 1 < NCH) {
      // stage next chunk into the other buffer (prev-iter bottom barrier
      // guarantees everyone finished reading it)
      const int d0 = (ic + 1) * 64;
      #pragma unroll
      for (int i = 0; i < 4; ++i) {
        int rbase = (wave * 4 + i) * 8;
        async16(xtb + (size_t)(rbase + rloc) * EINP + d0 + gsrc * 8,
                &sm.u.s.As[bf ^ 1][rbase * 64]);
        async16(w1k + (size_t)(rbase + rloc) * EINP + d0 + gsrc * 8,
                &sm.u.s.Bs[bf ^ 1][rbase * 64]);
      }
      asm volatile("s_waitcnt vmcnt(8)" ::: "memory");   // chunk ic landed; ic+1 in flight
    } else {
      asm volatile("s_waitcnt vmcnt(0)" ::: "memory");   // last chunk: drain
    }
    __builtin_amdgcn_s_barrier();
    __builtin_amdgcn_sched_barrier(0);

    const u16* Ab = sm.u.s.As[bf];
    const u16* Bb = sm.u.s.Bs[bf];
    __builtin_amdgcn_s_setprio(1);
    #pragma unroll
    for (int ks = 0; ks < 2; ++ks) {
      short8 a[4], b[4];
      #pragma unroll
      for (int m = 0; m < 4; ++m) {
        int r = wm * 64 + m * 16 + ln;
        int g = (ks * 4 + q) ^ (r & 7);
        a[m] = *(const short8*)(&Ab[r * 64 + g * 8]);
      }
      #pragma unroll
      for (int n = 0; n < 4; ++n) {
        int c = wn * 64 + n * 16 + ln;
        int g = (ks * 4 + q) ^ (c & 7);
        b[n] = *(const short8*)(&Bb[c * 64 + g * 8]);
      }
      #pragma unroll
      for (int m = 0; m < 4; ++m)
        #pragma unroll
        for (int n = 0; n < 4; ++n)
          acc[m][n] = __builtin_amdgcn_mfma_f32_16x16x32_bf16(a[m], b[n], acc[m][n], 0, 0, 0);
    }
    __builtin_amdgcn_s_setprio(0);
    __builtin_amdgcn_sched_barrier(0);
    __builtin_amdgcn_s_barrier();
  }
  __syncthreads();   // full drain before aliased LDS reuse (As2/Bs2 overlay)

  // ---------------- fused GEMM2: silu(acc+b1) @ W2t[e], K = 128 ----------------
  const u16* w2k = W2t + (size_t)e * HID * HID;
  // prefetch BOTH W2 chunks under the As2-write phase (8 async16 per wave)
  #pragma unroll
  for (int kc = 0; kc < 2; ++kc)
    #pragma unroll
    for (int i = 0; i < 4; ++i) {
      int rbase = (wave * 4 + i) * 8;
      async16(w2k + (size_t)(rbase + rloc) * HID + kc * 64 + gsrc * 8,
              &sm.u.g.Bs2[kc][rbase * 64]);
    }

  // Write the full 128x128 H1 tile as bf16 into As2, XOR-swizzled:
  // element (row,h) at As2[row*128 + ((h>>3)^(row&7))*8 + (h&7)]
  #pragma unroll
  for (int n = 0; n < 4; ++n) {
    int cl = wn * 64 + n * 16 + ln;            // h = 0..127
    float bv = b1[e * HID + cl];
    #pragma unroll
    for (int m = 0; m < 4; ++m)
      #pragma unroll
      for (int r = 0; r < 4; ++r) {
        int row = wm * 64 + m * 16 + q * 4 + r;
        sm.u.g.As2[row * 128 + (((cl >> 3) ^ (row & 7)) << 3) + (cl & 7)] =
            f2bf(silu(acc[m][n][r] + bv));
      }
  }

  f32x4 acc2[4][4];
  #pragma unroll
  for (int m = 0; m < 4; ++m)
    #pragma unroll
    for (int n = 0; n < 4; ++n) acc2[m][n] = fz;

  __syncthreads();   // As2 ds_writes visible + both Bs2 DMAs landed (full drain)

  #pragma unroll
  for (int kc = 0; kc < 2; ++kc) {
    #pragma unroll
    for (int ks = 0; ks < 2; ++ks) {
      short8 a[4], b[4];
      #pragma unroll
      for (int m = 0; m < 4; ++m) {
        int r = wm * 64 + m * 16 + ln;
        int G = kc * 8 + ks * 4 + q;           // 4-bit h-group
        int g = (G & 8) | ((G ^ (r & 7)) & 7);
        a[m] = *(const short8*)(&sm.u.g.As2[r * 128 + g * 8]);
      }
      #pragma unroll
      for (int n = 0; n < 4; ++n) {
        int c = wn * 64 + n * 16 + ln;
        int g = (ks * 4 + q) ^ (c & 7);
        b[n] = *(const short8*)(&sm.u.g.Bs2[kc][c * 64 + g * 8]);
      }
      #pragma unroll
      for (int m = 0; m < 4; ++m)
        #pragma unroll
        for (int n = 0; n < 4; ++n)
          acc2[m][n] = __builtin_amdgcn_mfma_f32_16x16x32_bf16(a[m], b[n], acc2[m][n], 0, 0, 0);
    }
  }
  __syncthreads();

  // ---------------- epilogue: p * silu(acc2 + b2) -> bf16 H, coalesced ----------------
  u16* hb = H + (size_t)m0 * NTOT + e * HID;
  #pragma unroll 1
  for (int hf = 0; hf < 2; ++hf) {
    if (wn == hf) {
      #pragma unroll
      for (int n = 0; n < 4; ++n) {
        int cl = n * 16 + ln;
        float bv = b2[e * HID + hf * 64 + cl];
        #pragma unroll
        for (int m = 0; m < 4; ++m)
          #pragma unroll
          for (int r = 0; r < 4; ++r) {
            int row = wm * 64 + m * 16 + q * 4 + r;
            sm.u.Cs[row * 72 + cl] = f2bf(sm.Ps[row] * silu(acc2[m][n][r] + bv));
          }
      }
    }
    __syncthreads();
    #pragma unroll
    for (int i = 0; i < 4; ++i) {
      int lin = tid + i * 256;
      int row = lin >> 3;
      int grp = lin & 7;
      *(u32x4*)(hb + (size_t)row * NTOT + hf * 64 + grp * 8) =
          *(const u32x4*)(&sm.u.Cs[row * 72 + grp * 8]);
    }
    __syncthreads();
  }
}

// ---------------------------------------------------------------------------
// FALLBACK PATH (only if ws_size too small for Xbf): previous-session
// h1_gemm + h2_gemm, verbatim.
// ---------------------------------------------------------------------------
__global__ __launch_bounds__(256, 4)
void h1_gemm(const float* __restrict__ cond, const float* __restrict__ uu,
             const float* __restrict__ tau, const u16* __restrict__ W1t,
             const float* __restrict__ b1, u16* __restrict__ H1) {
  __shared__ union {
    struct { u16 As[128 * 64]; u16 Bs[128 * 64]; } s;
    u16 Cs[128 * 72];
  } sm;

  const int tid  = threadIdx.x;
  const int wave = tid >> 6;
  const int lane = tid & 63;
  const int q    = lane >> 4;
  const int ln   = lane & 15;
  const int wm   = wave >> 1, wn = wave & 1;
  const int bid  = blockIdx.x;
  const int mt   = ((bid >> 6) << 3) | (bid & 7);
  const int e    = (bid >> 3) & 7;
  const int m0   = mt * 128, n0 = e * 128;
  const u16* w1k = W1t + (size_t)e * HID * EINP;

  const f32x4 fz = {0.f, 0.f, 0.f, 0.f};
  f32x4 acc[4][4];
  #pragma unroll
  for (int m = 0; m < 4; ++m)
    #pragma unroll
    for (int n = 0; n < 4; ++n) acc[m][n] = fz;

  #pragma unroll 1
  for (int ic = 0; ic < NCH; ++ic) {
    const int d0 = ic * 64;
    #pragma unroll
    for (int i = 0; i < 4; ++i) {
      int lin  = tid + i * 256;
      int row  = lin >> 3;
      int gsw  = lin & 7;
      int gsrc = gsw ^ (row & 7);
      int gr   = m0 + row;
      float f0, f1, f2, f3, f4, f5, f6, f7;
      if (d0 < 256) {
        const float4* p = (const float4*)(uu + (size_t)gr * LATENT + d0 + gsrc * 8);
        float4 A = p[0], Bv = p[1];
        f0 = A.x; f1 = A.y; f2 = A.z; f3 = A.w; f4 = Bv.x; f5 = Bv.y; f6 = Bv.z; f7 = Bv.w;
      } else if (d0 < 1280) {
        const float4* p = (const float4*)(cond + (size_t)gr * CONDD + (d0 - 256) + gsrc * 8);
        float4 A = p[0], Bv = p[1];
        f0 = A.x; f1 = A.y; f2 = A.z; f3 = A.w; f4 = Bv.x; f5 = Bv.y; f6 = Bv.z; f7 = Bv.w;
      } else {
        float tv = tau[gr];
        f0 = (gsrc == 0) ? tv : 0.f;
        f1 = f2 = f3 = f4 = f5 = f6 = f7 = 0.f;
      }
      u32x4 pk;
      pk[0] = (uint32_t)f2bf(f0) | ((uint32_t)f2bf(f1) << 16);
      pk[1] = (uint32_t)f2bf(f2) | ((uint32_t)f2bf(f3) << 16);
      pk[2] = (uint32_t)f2bf(f4) | ((uint32_t)f2bf(f5) << 16);
      pk[3] = (uint32_t)f2bf(f6) | ((uint32_t)f2bf(f7) << 16);
      *(u32x4*)(&sm.s.As[row * 64 + gsw * 8]) = pk;
    }
    {
      int rloc = lane >> 3;
      int gsw  = lane & 7;
      int gsrc = gsw ^ rloc;
      #pragma unroll
      for (int i = 0; i < 4; ++i) {
        int rbase = (wave * 4 + i) * 8;
        async16(w1k + (size_t)(rbase + rloc) * EINP + d0 + gsrc * 8,
                &sm.s.Bs[rbase * 64]);
      }
    }
    __syncthreads();
    #pragma unroll
    for (int ks = 0; ks < 2; ++ks) {
      short8 a[4], b[4];
      #pragma unroll
      for (int m = 0; m < 4; ++m) {
        int r = wm * 64 + m * 16 + ln;
        int g = (ks * 4 + q) ^ (r & 7);
        a[m] = *(const short8*)(&sm.s.As[r * 64 + g * 8]);
      }
      #pragma unroll
      for (int n = 0; n < 4; ++n) {
        int c = wn * 64 + n * 16 + ln;
        int g = (ks * 4 + q) ^ (c & 7);
        b[n] = *(const short8*)(&sm.s.Bs[c * 64 + g * 8]);
      }
      #pragma unroll
      for (int m = 0; m < 4; ++m)
        #pragma unroll
        for (int n = 0; n < 4; ++n)
          acc[m][n] = __builtin_amdgcn_mfma_f32_16x16x32_bf16(a[m], b[n], acc[m][n], 0, 0, 0);
    }
    __syncthreads();
  }

  #pragma unroll 1
  for (int hf = 0; hf < 2; ++hf) {
    if (wn == hf) {
      #pragma unroll
      for (int n = 0; n < 4; ++n) {
        int cl = n * 16 + ln;
        float bv = b1[n0 + hf * 64 + cl];
        #pragma unroll
        for (int m = 0; m < 4; ++m)
          #pragma unroll
          for (int r = 0; r < 4; ++r)
            sm.Cs[(wm * 64 + m * 16 + q * 4 + r) * 72 + cl] = f2bf(silu(acc[m][n][r] + bv));
      }
    }
    __syncthreads();
    #pragma unroll
    for (int i = 0; i < 4; ++i) {
      int lin = tid + i * 256;
      int row = lin >> 3;
      int grp = lin & 7;
      *(u32x4*)(H1 + (size_t)(m0 + row) * NTOT + n0 + hf * 64 + grp * 8) =
          *(const u32x4*)(&sm.Cs[row * 72 + grp * 8]);
    }
    __syncthreads();
  }
}

__global__ __launch_bounds__(256, 4)
void h2_gemm(u16* __restrict__ H, const float* __restrict__ p_hat,
             const u16* __restrict__ W2t, const float* __restrict__ b2) {
  __shared__ struct {
    union { struct { u16 As[128 * 64]; u16 Bs[128 * 64]; } s; u16 Cs[128 * 72]; } u;
    float Ps[128];
  } sm;

  const int tid  = threadIdx.x;
  const int wave = tid >> 6;
  const int lane = tid & 63;
  const int q    = lane >> 4;
  const int ln   = lane & 15;
  const int wm   = wave >> 1, wn = wave & 1;
  const int mt   = blockIdx.x >> 3;
  const int e    = blockIdx.x & 7;
  const int row0 = mt * 128;

  if (tid < 128) sm.Ps[tid] = p_hat[(size_t)(row0 + tid) * KEXP + e];

  const u16* w2k = W2t + (size_t)e * HID * HID;
  u16* hb = H + (size_t)row0 * NTOT + e * HID;

  const f32x4 fz = {0.f, 0.f, 0.f, 0.f};
  f32x4 acc[4][4];
  #pragma unroll
  for (int m = 0; m < 4; ++m)
    #pragma unroll
    for (int n = 0; n < 4; ++n) acc[m][n] = fz;

  const int rloc = lane >> 3;
  const int gsw  = lane & 7;
  const int gsrc = gsw ^ rloc;

  #pragma unroll 1
  for (int kc = 0; kc < 2; ++kc) {
    #pragma unroll
    for (int i = 0; i < 4; ++i) {
      int rbase = (wave * 4 + i) * 8;
      async16(hb + (size_t)(rbase + rloc) * NTOT + kc * 64 + gsrc * 8,
              &sm.u.s.As[rbase * 64]);
      async16(w2k + (size_t)(rbase + rloc) * HID + kc * 64 + gsrc * 8,
              &sm.u.s.Bs[rbase * 64]);
    }
    __syncthreads();
    #pragma unroll
    for (int ks = 0; ks < 2; ++ks) {
      short8 a[4], b[4];
      #pragma unroll
      for (int m = 0; m < 4; ++m) {
        int r = wm * 64 + m * 16 + ln;
        int g = (ks * 4 + q) ^ (r & 7);
        a[m] = *(const short8*)(&sm.u.s.As[r * 64 + g * 8]);
      }
      #pragma unroll
      for (int n = 0; n < 4; ++n) {
        int c = wn * 64 + n * 16 + ln;
        int g = (ks * 4 + q) ^ (c & 7);
        b[n] = *(const short8*)(&sm.u.s.Bs[c * 64 + g * 8]);
      }
      #pragma unroll
      for (int m = 0; m < 4; ++m)
        #pragma unroll
        for (int n = 0; n < 4; ++n)
          acc[m][n] = __builtin_amdgcn_mfma_f32_16x16x32_bf16(a[m], b[n], acc[m][n], 0, 0, 0);
    }
    __syncthreads();
  }

  #pragma unroll 1
  for (int hf = 0; hf < 2; ++hf) {
    if (wn == hf) {
      #pragma unroll
      for (int n = 0; n < 4; ++n) {
        int cl = n * 16 + ln;
        float bv = b2[e * HID + hf * 64 + cl];
        #pragma unroll
        for (int m = 0; m < 4; ++m)
          #pragma unroll
          for (int r = 0; r < 4; ++r) {
            int row = wm * 64 + m * 16 + q * 4 + r;
            sm.u.Cs[row * 72 + cl] = f2bf(sm.Ps[row] * silu(acc[m][n][r] + bv));
          }
      }
    }
    __syncthreads();
    #pragma unroll
    for (int i = 0; i < 4; ++i) {
      int lin = tid + i * 256;
      int row = lin >> 3;
      int grp = lin & 7;
      *(u32x4*)(hb + (size_t)row * NTOT + hf * 64 + grp * 8) =
          *(const u32x4*)(&sm.u.Cs[row * 72 + grp * 8]);
    }
    __syncthreads();
  }
}

// ---------------------------------------------------------------------------
// out_gemm: out = Hg @ W3t2^T + (p @ b3). M=32768 N=256 K=1024.
// T3/T4 pipeline: dbuf As/Bs, vmcnt(6) counted waits. 54 KB -> 2 blk/CU.
// ---------------------------------------------------------------------------
__global__ __launch_bounds__(256, 2)
void out_gemm(const u16* __restrict__ H, const float* __restrict__ p_hat,
              const u16* __restrict__ W3t2, const float* __restrict__ b3,
              float* __restrict__ out) {
  __shared__ struct {
    u16 As[2][64 * 64];   // 16 KB
    u16 Bs[2][128 * 64];  // 32 KB
    float Ps[64 * 8];     // 2 KB
    float B3s[128 * 8];   // 4 KB
  } sm;

  const int tid  = threadIdx.x;
  const int wave = tid >> 6;
  const int lane = tid & 63;
  const int q    = lane >> 4;
  const int ln   = lane & 15;
  const int bid  = blockIdx.x;
  const int mt   = ((bid >> 4) << 3) | (bid & 7);   // 0..511
  const int bn   = (bid >> 3) & 1;
  const int m0   = mt * 64, n0 = bn * 128;

  // stage p rows (64 x 8) and b3 columns (128 x 8, transposed)
  if (tid < 128) {
    int row = tid >> 1, h = tid & 1;
    *(float4*)(&sm.Ps[row * 8 + h * 4]) = *(const float4*)(p_hat + (size_t)(m0 + row) * KEXP + h * 4);
  }
  #pragma unroll
  for (int i = 0; i < 4; ++i) {
    int k = i * 2 + (tid >> 7);
    int c = tid & 127;
    sm.B3s[c * 8 + k] = b3[k * LATENT + n0 + c];
  }

  const f32x4 fz = {0.f, 0.f, 0.f, 0.f};
  f32x4 acc[4][2];
  #pragma unroll
  for (int m = 0; m < 4; ++m) { acc[m][0] = fz; acc[m][1] = fz; }

  const int rloc = lane >> 3;
  const int gsw  = lane & 7;
  const int gsrc = gsw ^ rloc;

  // prologue: stage chunk 0 into buffer 0 (6 async16 per wave)
  #pragma unroll
  for (int i = 0; i < 2; ++i) {
    int rbase = (wave * 2 + i) * 8;
    async16(H + (size_t)(m0 + rbase + rloc) * NTOT + gsrc * 8, &sm.As[0][rbase * 64]);
  }
  #pragma unroll
  for (int i = 0; i < 4; ++i) {
    int rbase = (wave * 4 + i) * 8;
    async16(W3t2 + (size_t)(n0 + rbase + rloc) * NTOT + gsrc * 8, &sm.Bs[0][rbase * 64]);
  }

  #pragma unroll 1
  for (int kc = 0; kc < 16; ++kc) {
    const int bf = kc & 1;
    if (kc + 1 < 16) {
      const int d0 = (kc + 1) * 64;
      #pragma unroll
      for (int i = 0; i < 2; ++i) {
        int rbase = (wave * 2 + i) * 8;
        async16(H + (size_t)(m0 + rbase + rloc) * NTOT + d0 + gsrc * 8,
                &sm.As[bf ^ 1][rbase * 64]);
      }
      #pragma unroll
      for (int i = 0; i < 4; ++i) {
        int rbase = (wave * 4 + i) * 8;
        async16(W3t2 + (size_t)(n0 + rbase + rloc) * NTOT + d0 + gsrc * 8,
                &sm.Bs[bf ^ 1][rbase * 64]);
      }
      asm volatile("s_waitcnt vmcnt(6)" ::: "memory");   // chunk kc landed
    } else {
      asm volatile("s_waitcnt vmcnt(0)" ::: "memory");
    }
    __builtin_amdgcn_s_barrier();
    __builtin_amdgcn_sched_barrier(0);

    const u16* Ab = sm.As[bf];
    const u16* Bb = sm.Bs[bf];
    __builtin_amdgcn_s_setprio(1);
    #pragma unroll
    for (int ks = 0; ks < 2; ++ks) {
      short8 a[4], b[2];
      #pragma unroll
      for (int m = 0; m < 4; ++m) {
        int r = m * 16 + ln;
        int g = (ks * 4 + q) ^ (r & 7);
        a[m] = *(const short8*)(&Ab[r * 64 + g * 8]);
      }
      #pragma unroll
      for (int n = 0; n < 2; ++n) {
        int c = wave * 32 + n * 16 + ln;
        int g = (ks * 4 + q) ^ (c & 7);
        b[n] = *(const short8*)(&Bb[c * 64 + g * 8]);
      }
      #pragma unroll
      for (int m = 0; m < 4; ++m)
        #pragma unroll
        for (int n = 0; n < 2; ++n)
          acc[m][n] = __builtin_amdgcn_mfma_f32_16x16x32_bf16(a[m], b[n], acc[m][n], 0, 0, 0);
    }
    __builtin_amdgcn_s_setprio(0);
    __builtin_amdgcn_sched_barrier(0);
    __builtin_amdgcn_s_barrier();
  }
  __syncthreads();

  // ---- epilogue: + sum_k p[row][k]*b3[k][col], fp32 store ----
  #pragma unroll
  for (int n = 0; n < 2; ++n) {
    int col = wave * 32 + n * 16 + ln;
    float4 c0 = *(const float4*)(&sm.B3s[col * 8]);
    float4 c1 = *(const float4*)(&sm.B3s[col * 8 + 4]);
    #pragma unroll
    for (int m = 0; m < 4; ++m)
      #pragma unroll
      for (int r = 0; r < 4; ++r) {
        int row = m * 16 + q * 4 + r;
        float4 p0 = *(const float4*)(&sm.Ps[row * 8]);
        float4 p1 = *(const float4*)(&sm.Ps[row * 8 + 4]);
        float v = acc[m][n][r]
                + p0.x * c0.x + p0.y * c0.y + p0.z * c0.z + p0.w * c0.w
                + p1.x * c1.x + p1.y * c1.y + p1.z * c1.z + p1.w * c1.w;
        out[(size_t)(m0 + row) * LATENT + n0 + col] = v;
      }
  }
}

extern "C" void kernel_launch(void* const* d_in, const int* in_sizes, int n_in,
                              void* d_out, int out_size, void* d_ws, size_t ws_size,
                              hipStream_t stream) {
  const float* cond  = (const float*)d_in[0];
  const float* u     = (const float*)d_in[1];
  const float* tau   = (const float*)d_in[2];
  const float* p_hat = (const float*)d_in[3];
  const float* W1    = (const float*)d_in[4];
  const float* b1    = (const float*)d_in[5];
  const float* W2    = (const float*)d_in[6];
  const float* b2    = (const float*)d_in[7];
  const float* W3    = (const float*)d_in[8];
  const float* b3    = (const float*)d_in[9];
  float* out = (float*)d_out;

  const size_t N1 = (size_t)KEXP * HID * EINP;    // 1,376,256
  const size_t N2 = (size_t)KEXP * HID * HID;     //   131,072
  const size_t N3 = (size_t)LATENT * NTOT;        //   262,144
  const size_t NH = (size_t)BROWS * NTOT;         // 33,554,432
  const size_t NX = (size_t)BROWS * EINP;         // 44,040,192 (bf16 X)

  u16* W1t  = (u16*)d_ws;
  u16* W2t  = W1t + N1;
  u16* W3t2 = W2t + N2;
  u16* H    = W3t2 + N3;

  if (ws_size >= (N1 + N2 + N3 + NH + NX) * sizeof(u16)) {
    // ---- fast path: bf16 X prepass + pipelined fused h1+h2 ----
    u16* Xbf = H + NH;
    conv_w<<<W1_TILES + W2_TILES + W3_TILES, 256, 0, stream>>>(W1, W2, W3, W1t, W2t, W3t2);
    x_conv<<<XGRP / 256, 256, 0, stream>>>(cond, u, tau, Xbf);
    h1_fused<<<2048, 256, 0, stream>>>(Xbf, W1t, b1, W2t, b2, p_hat, H);
    out_gemm<<<1024, 256, 0, stream>>>(H, p_hat, W3t2, b3, out);
  } else if (ws_size >= (N1 + N2 + N3 + NH) * sizeof(u16)) {
    // ---- fallback: previous-session path ----
    conv_w<<<W1_TILES + W2_TILES + W3_TILES, 256, 0, stream>>>(W1, W2, W3, W1t, W2t, W3t2);
    h1_gemm<<<2048, 256, 0, stream>>>(cond, u, tau, W1t, b1, H);
    h2_gemm<<<2048, 256, 0, stream>>>(H, p_hat, W2t, b2);
    out_gemm<<<1024, 256, 0, stream>>>(H, p_hat, W3t2, b3, out);
  }
}

// Round 4
// 431.745 us; speedup vs baseline: 1.2345x; 1.0091x over previous
//
#include <hip/hip_runtime.h>
#include <stdint.h>

typedef unsigned short u16;
typedef __attribute__((ext_vector_type(8))) short short8;   // 8 x bf16 MFMA operand
typedef __attribute__((ext_vector_type(4))) float f32x4;    // MFMA accumulator
typedef __attribute__((ext_vector_type(4))) uint32_t u32x4;

#define KEXP   8
#define LATENT 256
#define CONDD  1024
#define HID    128
#define EIN    1281
#define EINP   1344   // 21*64, zero padded
#define NCH    21
#define NTOT   1024   // KEXP*HID
#define BROWS  32768

__device__ __forceinline__ u16 f2bf(float x) {              // RNE fp32->bf16
  uint32_t v = __float_as_uint(x);
  v += 0x7fffu + ((v >> 16) & 1u);
  return (u16)(v >> 16);
}

__device__ __forceinline__ void async16(const void* g, void* l) {
  __builtin_amdgcn_global_load_lds(
      (const __attribute__((address_space(1))) void*)g,
      (__attribute__((address_space(3))) void*)l, 16, 0, 0);
}

__device__ __forceinline__ float silu(float x) { return x / (1.f + __expf(-x)); }

// ---------------------------------------------------------------------------
// prep: merged conv_w (1728 blocks) + x_conv (21504 blocks), one launch.
// conv: coalesced 32x32 LDS-tiled transpose -> bf16.
//   W1t[k][h][d] (d pad 1344), W2t[k][g][h], W3t2[l][k*128+g] (256 x 1024)
// x:   Xbf[b][1344] = bf16(concat(u, cond, tau, 0-pad)), 16B stores.
// ---------------------------------------------------------------------------
#define W1_TILES (KEXP * 42 * 4)    // 1344
#define W2_TILES (KEXP * 4 * 4)     // 128
#define W3_TILES (KEXP * 4 * 8)     // 256
#define WCONV_TILES (W1_TILES + W2_TILES + W3_TILES)   // 1728
#define XGRP (BROWS * 168)
#define XBLK (XGRP / 256)           // 21504

__global__ __launch_bounds__(256)
void prep(const float* __restrict__ W1, const float* __restrict__ W2,
          const float* __restrict__ W3, const float* __restrict__ cond,
          const float* __restrict__ uu, const float* __restrict__ tau,
          u16* __restrict__ W1t, u16* __restrict__ W2t, u16* __restrict__ W3t2,
          u16* __restrict__ Xbf) {
  __shared__ float t[32][33];
  const int bid = blockIdx.x;
  if (bid >= WCONV_TILES) {
    // ---- x_conv path ----
    int g = (bid - WCONV_TILES) * 256 + threadIdx.x;
    int row = g / 168;
    int c8  = g - row * 168;
    float f0 = 0.f, f1 = 0.f, f2 = 0.f, f3 = 0.f, f4 = 0.f, f5 = 0.f, f6 = 0.f, f7 = 0.f;
    if (c8 < 32) {
      const float4* p = (const float4*)(uu + (size_t)row * LATENT + c8 * 8);
      float4 a = p[0], b = p[1];
      f0 = a.x; f1 = a.y; f2 = a.z; f3 = a.w; f4 = b.x; f5 = b.y; f6 = b.z; f7 = b.w;
    } else if (c8 < 160) {
      const float4* p = (const float4*)(cond + (size_t)row * CONDD + (c8 - 32) * 8);
      float4 a = p[0], b = p[1];
      f0 = a.x; f1 = a.y; f2 = a.z; f3 = a.w; f4 = b.x; f5 = b.y; f6 = b.z; f7 = b.w;
    } else if (c8 == 160) {
      f0 = tau[row];                       // col 1280; 1281.. zero
    }
    u32x4 pk;
    pk[0] = (uint32_t)f2bf(f0) | ((uint32_t)f2bf(f1) << 16);
    pk[1] = (uint32_t)f2bf(f2) | ((uint32_t)f2bf(f3) << 16);
    pk[2] = (uint32_t)f2bf(f4) | ((uint32_t)f2bf(f5) << 16);
    pk[3] = (uint32_t)f2bf(f6) | ((uint32_t)f2bf(f7) << 16);
    *(u32x4*)(Xbf + (size_t)row * EINP + c8 * 8) = pk;
    return;
  }
  // ---- conv_w path ----
  const int tx = threadIdx.x & 31, ty = threadIdx.x >> 5;   // 32 x 8
  if (bid < W1_TILES) {
    int k = bid / 168, r = bid % 168;
    int d0 = (r / 4) * 32, h0 = (r % 4) * 32;
    const float* src = W1 + (size_t)k * EIN * HID;
    #pragma unroll
    for (int s = 0; s < 4; ++s) {
      int d = d0 + ty + s * 8;
      t[ty + s * 8][tx] = (d < EIN) ? src[(size_t)d * HID + h0 + tx] : 0.f;
    }
    __syncthreads();
    u16* dst = W1t + (size_t)k * HID * EINP;
    #pragma unroll
    for (int s = 0; s < 4; ++s)
      dst[(size_t)(h0 + ty + s * 8) * EINP + d0 + tx] = f2bf(t[tx][ty + s * 8]);
  } else if (bid < W1_TILES + W2_TILES) {
    int j = bid - W1_TILES;
    int k = j / 16, r = j % 16;
    int d0 = (r / 4) * 32, h0 = (r % 4) * 32;
    const float* src = W2 + (size_t)k * HID * HID;
    #pragma unroll
    for (int s = 0; s < 4; ++s)
      t[ty + s * 8][tx] = src[(size_t)(d0 + ty + s * 8) * HID + h0 + tx];
    __syncthreads();
    u16* dst = W2t + (size_t)k * HID * HID;
    #pragma unroll
    for (int s = 0; s < 4; ++s)
      dst[(size_t)(h0 + ty + s * 8) * HID + d0 + tx] = f2bf(t[tx][ty + s * 8]);
  } else {
    int j = bid - W1_TILES - W2_TILES;
    int k = j / 32, r = j % 32;
    int d0 = (r / 8) * 32, h0 = (r % 8) * 32;   // d=g (128), h=l (256)
    const float* src = W3 + (size_t)k * HID * LATENT;
    #pragma unroll
    for (int s = 0; s < 4; ++s)
      t[ty + s * 8][tx] = src[(size_t)(d0 + ty + s * 8) * LATENT + h0 + tx];
    __syncthreads();
    #pragma unroll
    for (int s = 0; s < 4; ++s)
      W3t2[(size_t)(h0 + ty + s * 8) * NTOT + k * HID + d0 + tx] = f2bf(t[tx][ty + s * 8]);
  }
}

// ---------------------------------------------------------------------------
// h1_fused: H[:, e*128:] = p[:,e] * silu( silu(X@W1t[e]+b1) @ W2t[e] + b2 ).
// Canonical 2-phase dbuf: per chunk { stage(t+1)->buf^1; MFMA(buf);
// vmcnt(0); barrier } — ONE barrier per chunk.  K-loop hand-unrolled by 2
// so the buffer index is compile-time -> LDS addresses are loop-invariant
// (kills per-chunk VALU address re-materialization).
// LDS 64.5 KB -> 2 blocks/CU; setprio around MFMA.
// ---------------------------------------------------------------------------
__global__ __launch_bounds__(256, 2)
void h1_fused(const u16* __restrict__ Xbf, const u16* __restrict__ W1t,
              const float* __restrict__ b1, const u16* __restrict__ W2t,
              const float* __restrict__ b2, const float* __restrict__ p_hat,
              u16* __restrict__ H) {
  __shared__ struct {
    union {
      struct { u16 As[2][128 * 64]; u16 Bs[2][128 * 64]; } s;   // 64 KB staging
      struct { u16 As2[128 * 128]; u16 Bs2[2][128 * 64]; } g;   // 64 KB GEMM2
      u16 Cs[128 * 72];                                         // 18 KB epilogue
    } u;
    float Ps[128];
  } sm;

  const int tid  = threadIdx.x;
  const int wave = tid >> 6;
  const int lane = tid & 63;
  const int q    = lane >> 4;
  const int ln   = lane & 15;
  const int wm   = wave >> 1, wn = wave & 1;
  const int bid  = blockIdx.x;
  const int mt   = ((bid >> 6) << 3) | (bid & 7);   // 0..255, same-XCD siblings
  const int e    = (bid >> 3) & 7;                  // expert
  const int m0   = mt * 128;
  const u16* w1k = W1t + (size_t)e * HID * EINP;
  const u16* xtb = Xbf + (size_t)m0 * EINP;

  if (tid < 128) sm.Ps[tid] = p_hat[(size_t)(m0 + tid) * KEXP + e];

  const f32x4 fz = {0.f, 0.f, 0.f, 0.f};
  f32x4 acc[4][4];
  #pragma unroll
  for (int m = 0; m < 4; ++m)
    #pragma unroll
    for (int n = 0; n < 4; ++n) acc[m][n] = fz;

  const int rloc = lane >> 3;
  const int gsw  = lane & 7;
  const int gsrc = gsw ^ rloc;      // pre-swizzled global source, linear LDS dest

  // stage chunk at byte-col d0 into buffer bf (bf compile-time at call sites)
  auto stage = [&](int d0, int bf) {
    #pragma unroll
    for (int i = 0; i < 4; ++i) {
      int rbase = (wave * 4 + i) * 8;
      async16(xtb + (size_t)(rbase + rloc) * EINP + d0 + gsrc * 8,
              &sm.u.s.As[bf][rbase * 64]);
      async16(w1k + (size_t)(rbase + rloc) * EINP + d0 + gsrc * 8,
              &sm.u.s.Bs[bf][rbase * 64]);
    }
  };
  // one chunk of MFMAs from buffer bf (compile-time)
  auto mfma_chunk = [&](int bf) {
    const u16* Ab = sm.u.s.As[bf];
    const u16* Bb = sm.u.s.Bs[bf];
    __builtin_amdgcn_s_setprio(1);
    #pragma unroll
    for (int ks = 0; ks < 2; ++ks) {
      short8 a[4], b[4];
      #pragma unroll
      for (int m = 0; m < 4; ++m) {
        int r = wm * 64 + m * 16 + ln;
        int g = (ks * 4 + q) ^ (r & 7);
        a[m] = *(const short8*)(&Ab[r * 64 + g * 8]);
      }
      #pragma unroll
      for (int n = 0; n < 4; ++n) {
        int c = wn * 64 + n * 16 + ln;
        int g = (ks * 4 + q) ^ (c & 7);
        b[n] = *(const short8*)(&Bb[c * 64 + g * 8]);
      }
      #pragma unroll
      for (int m = 0; m < 4; ++m)
        #pragma unroll
        for (int n = 0; n < 4; ++n)
          acc[m][n] = __builtin_amdgcn_mfma_f32_16x16x32_bf16(a[m], b[n], acc[m][n], 0, 0, 0);
    }
    __builtin_amdgcn_s_setprio(0);
  };

  // ---------------- GEMM1: X @ W1t, K = 1344 = 21 chunks ----------------
  // prologue: chunk 0 -> buf0, drain, barrier
  stage(0, 0);
  asm volatile("s_waitcnt vmcnt(0)" ::: "memory");
  __builtin_amdgcn_s_barrier();
  __builtin_amdgcn_sched_barrier(0);

  #pragma unroll 1
  for (int ic2 = 0; ic2 < 10; ++ic2) {
    const int d = ic2 * 128;
    // chunk 2*ic2 (buf0); prefetch 2*ic2+1 -> buf1
    stage(d + 64, 1);
    mfma_chunk(0);
    asm volatile("s_waitcnt vmcnt(0)" ::: "memory");
    __builtin_amdgcn_s_barrier();
    __builtin_amdgcn_sched_barrier(0);
    // chunk 2*ic2+1 (buf1); prefetch 2*ic2+2 -> buf0  (max d+128 = 1280 ✓)
    stage(d + 128, 0);
    mfma_chunk(1);
    asm volatile("s_waitcnt vmcnt(0)" ::: "memory");
    __builtin_amdgcn_s_barrier();
    __builtin_amdgcn_sched_barrier(0);
  }
  // tail: chunk 20 (buf0), already staged + drained + barriered
  mfma_chunk(0);
  __syncthreads();   // all staging reads done before aliased LDS overlay

  // ---------------- fused GEMM2: silu(acc+b1) @ W2t[e], K = 128 ----------------
  const u16* w2k = W2t + (size_t)e * HID * HID;
  // prefetch BOTH W2 chunks under the As2-write phase (8 async16 per wave)
  #pragma unroll
  for (int kc = 0; kc < 2; ++kc)
    #pragma unroll
    for (int i = 0; i < 4; ++i) {
      int rbase = (wave * 4 + i) * 8;
      async16(w2k + (size_t)(rbase + rloc) * HID + kc * 64 + gsrc * 8,
              &sm.u.g.Bs2[kc][rbase * 64]);
    }

  // Write the full 128x128 H1 tile as bf16 into As2, XOR-swizzled:
  // element (row,h) at As2[row*128 + ((h>>3)^(row&7))*8 + (h&7)]
  #pragma unroll
  for (int n = 0; n < 4; ++n) {
    int cl = wn * 64 + n * 16 + ln;            // h = 0..127
    float bv = b1[e * HID + cl];
    #pragma unroll
    for (int m = 0; m < 4; ++m)
      #pragma unroll
      for (int r = 0; r < 4; ++r) {
        int row = wm * 64 + m * 16 + q * 4 + r;
        sm.u.g.As2[row * 128 + (((cl >> 3) ^ (row & 7)) << 3) + (cl & 7)] =
            f2bf(silu(acc[m][n][r] + bv));
      }
  }

  f32x4 acc2[4][4];
  #pragma unroll
  for (int m = 0; m < 4; ++m)
    #pragma unroll
    for (int n = 0; n < 4; ++n) acc2[m][n] = fz;

  __syncthreads();   // As2 ds_writes visible + both Bs2 DMAs landed (full drain)

  #pragma unroll
  for (int kc = 0; kc < 2; ++kc) {
    #pragma unroll
    for (int ks = 0; ks < 2; ++ks) {
      short8 a[4], b[4];
      #pragma unroll
      for (int m = 0; m < 4; ++m) {
        int r = wm * 64 + m * 16 + ln;
        int G = kc * 8 + ks * 4 + q;           // 4-bit h-group
        int g = (G & 8) | ((G ^ (r & 7)) & 7);
        a[m] = *(const short8*)(&sm.u.g.As2[r * 128 + g * 8]);
      }
      #pragma unroll
      for (int n = 0; n < 4; ++n) {
        int c = wn * 64 + n * 16 + ln;
        int g = (ks * 4 + q) ^ (c & 7);
        b[n] = *(const short8*)(&sm.u.g.Bs2[kc][c * 64 + g * 8]);
      }
      #pragma unroll
      for (int m = 0; m < 4; ++m)
        #pragma unroll
        for (int n = 0; n < 4; ++n)
          acc2[m][n] = __builtin_amdgcn_mfma_f32_16x16x32_bf16(a[m], b[n], acc2[m][n], 0, 0, 0);
    }
  }
  __syncthreads();

  // ---------------- epilogue: p * silu(acc2 + b2) -> bf16 H, coalesced ----------------
  u16* hb = H + (size_t)m0 * NTOT + e * HID;
  #pragma unroll 1
  for (int hf = 0; hf < 2; ++hf) {
    if (wn == hf) {
      #pragma unroll
      for (int n = 0; n < 4; ++n) {
        int cl = n * 16 + ln;
        float bv = b2[e * HID + hf * 64 + cl];
        #pragma unroll
        for (int m = 0; m < 4; ++m)
          #pragma unroll
          for (int r = 0; r < 4; ++r) {
            int row = wm * 64 + m * 16 + q * 4 + r;
            sm.u.Cs[row * 72 + cl] = f2bf(sm.Ps[row] * silu(acc2[m][n][r] + bv));
          }
      }
    }
    __syncthreads();
    #pragma unroll
    for (int i = 0; i < 4; ++i) {
      int lin = tid + i * 256;
      int row = lin >> 3;
      int grp = lin & 7;
      *(u32x4*)(hb + (size_t)row * NTOT + hf * 64 + grp * 8) =
          *(const u32x4*)(&sm.u.Cs[row * 72 + grp * 8]);
    }
    __syncthreads();
  }
}

// ---------------------------------------------------------------------------
// out_gemm: out = Hg @ W3t2^T + (p @ b3). M=32768 N=256 K=1024.
// Same canonical 2-phase dbuf, one barrier per chunk, unroll-2.
// 54 KB -> 2 blk/CU.
// ---------------------------------------------------------------------------
__global__ __launch_bounds__(256, 2)
void out_gemm(const u16* __restrict__ H, const float* __restrict__ p_hat,
              const u16* __restrict__ W3t2, const float* __restrict__ b3,
              float* __restrict__ out) {
  __shared__ struct {
    u16 As[2][64 * 64];   // 16 KB
    u16 Bs[2][128 * 64];  // 32 KB
    float Ps[64 * 8];     // 2 KB
    float B3s[128 * 8];   // 4 KB
  } sm;

  const int tid  = threadIdx.x;
  const int wave = tid >> 6;
  const int lane = tid & 63;
  const int q    = lane >> 4;
  const int ln   = lane & 15;
  const int bid  = blockIdx.x;
  const int mt   = ((bid >> 4) << 3) | (bid & 7);   // 0..511
  const int bn   = (bid >> 3) & 1;
  const int m0   = mt * 64, n0 = bn * 128;

  // stage p rows (64 x 8) and b3 columns (128 x 8, transposed)
  if (tid < 128) {
    int row = tid >> 1, h = tid & 1;
    *(float4*)(&sm.Ps[row * 8 + h * 4]) = *(const float4*)(p_hat + (size_t)(m0 + row) * KEXP + h * 4);
  }
  #pragma unroll
  for (int i = 0; i < 4; ++i) {
    int k = i * 2 + (tid >> 7);
    int c = tid & 127;
    sm.B3s[c * 8 + k] = b3[k * LATENT + n0 + c];
  }

  const f32x4 fz = {0.f, 0.f, 0.f, 0.f};
  f32x4 acc[4][2];
  #pragma unroll
  for (int m = 0; m < 4; ++m) { acc[m][0] = fz; acc[m][1] = fz; }

  const int rloc = lane >> 3;
  const int gsw  = lane & 7;
  const int gsrc = gsw ^ rloc;

  auto stage = [&](int d0, int bf) {
    #pragma unroll
    for (int i = 0; i < 2; ++i) {
      int rbase = (wave * 2 + i) * 8;
      async16(H + (size_t)(m0 + rbase + rloc) * NTOT + d0 + gsrc * 8,
              &sm.As[bf][rbase * 64]);
    }
    #pragma unroll
    for (int i = 0; i < 4; ++i) {
      int rbase = (wave * 4 + i) * 8;
      async16(W3t2 + (size_t)(n0 + rbase + rloc) * NTOT + d0 + gsrc * 8,
              &sm.Bs[bf][rbase * 64]);
    }
  };
  auto mfma_chunk = [&](int bf) {
    const u16* Ab = sm.As[bf];
    const u16* Bb = sm.Bs[bf];
    __builtin_amdgcn_s_setprio(1);
    #pragma unroll
    for (int ks = 0; ks < 2; ++ks) {
      short8 a[4], b[2];
      #pragma unroll
      for (int m = 0; m < 4; ++m) {
        int r = m * 16 + ln;
        int g = (ks * 4 + q) ^ (r & 7);
        a[m] = *(const short8*)(&Ab[r * 64 + g * 8]);
      }
      #pragma unroll
      for (int n = 0; n < 2; ++n) {
        int c = wave * 32 + n * 16 + ln;
        int g = (ks * 4 + q) ^ (c & 7);
        b[n] = *(const short8*)(&Bb[c * 64 + g * 8]);
      }
      #pragma unroll
      for (int m = 0; m < 4; ++m)
        #pragma unroll
        for (int n = 0; n < 2; ++n)
          acc[m][n] = __builtin_amdgcn_mfma_f32_16x16x32_bf16(a[m], b[n], acc[m][n], 0, 0, 0);
    }
    __builtin_amdgcn_s_setprio(0);
  };

  // prologue: chunk 0 -> buf0; drain (also covers Ps/B3s ds_writes); barrier
  stage(0, 0);
  asm volatile("s_waitcnt vmcnt(0)" ::: "memory");
  __builtin_amdgcn_s_barrier();
  __builtin_amdgcn_sched_barrier(0);

  #pragma unroll 1
  for (int k2 = 0; k2 < 8; ++k2) {
    const int d = k2 * 128;
    // chunk 2*k2 (buf0); prefetch 2*k2+1 -> buf1
    stage(d + 64, 1);
    mfma_chunk(0);
    asm volatile("s_waitcnt vmcnt(0)" ::: "memory");
    __builtin_amdgcn_s_barrier();
    __builtin_amdgcn_sched_barrier(0);
    // chunk 2*k2+1 (buf1); prefetch 2*k2+2 -> buf0 (skip past last)
    if (k2 < 7) {
      stage(d + 128, 0);
      mfma_chunk(1);
      asm volatile("s_waitcnt vmcnt(0)" ::: "memory");
      __builtin_amdgcn_s_barrier();
      __builtin_amdgcn_sched_barrier(0);
    }
  }
  // tail: chunk 15 (buf1), staged + drained + barriered
  mfma_chunk(1);

  // ---- epilogue: + sum_k p[row][k]*b3[k][col], fp32 store ----
  #pragma unroll
  for (int n = 0; n < 2; ++n) {
    int col = wave * 32 + n * 16 + ln;
    float4 c0 = *(const float4*)(&sm.B3s[col * 8]);
    float4 c1 = *(const float4*)(&sm.B3s[col * 8 + 4]);
    #pragma unroll
    for (int m = 0; m < 4; ++m)
      #pragma unroll
      for (int r = 0; r < 4; ++r) {
        int row = m * 16 + q * 4 + r;
        float4 p0 = *(const float4*)(&sm.Ps[row * 8]);
        float4 p1 = *(const float4*)(&sm.Ps[row * 8 + 4]);
        float v = acc[m][n][r]
                + p0.x * c0.x + p0.y * c0.y + p0.z * c0.z + p0.w * c0.w
                + p1.x * c1.x + p1.y * c1.y + p1.z * c1.z + p1.w * c1.w;
        out[(size_t)(m0 + row) * LATENT + n0 + col] = v;
      }
  }
}

// ---------------------------------------------------------------------------
// FALLBACK PATH (only if ws_size too small for Xbf): previous-session
// h1_gemm + h2_gemm, verbatim.
// ---------------------------------------------------------------------------
__global__ __launch_bounds__(256, 4)
void h1_gemm(const float* __restrict__ cond, const float* __restrict__ uu,
             const float* __restrict__ tau, const u16* __restrict__ W1t,
             const float* __restrict__ b1, u16* __restrict__ H1) {
  __shared__ union {
    struct { u16 As[128 * 64]; u16 Bs[128 * 64]; } s;
    u16 Cs[128 * 72];
  } sm;

  const int tid  = threadIdx.x;
  const int wave = tid >> 6;
  const int lane = tid & 63;
  const int q    = lane >> 4;
  const int ln   = lane & 15;
  const int wm   = wave >> 1, wn = wave & 1;
  const int bid  = blockIdx.x;
  const int mt   = ((bid >> 6) << 3) | (bid & 7);
  const int e    = (bid >> 3) & 7;
  const int m0   = mt * 128, n0 = e * 128;
  const u16* w1k = W1t + (size_t)e * HID * EINP;

  const f32x4 fz = {0.f, 0.f, 0.f, 0.f};
  f32x4 acc[4][4];
  #pragma unroll
  for (int m = 0; m < 4; ++m)
    #pragma unroll
    for (int n = 0; n < 4; ++n) acc[m][n] = fz;

  #pragma unroll 1
  for (int ic = 0; ic < NCH; ++ic) {
    const int d0 = ic * 64;
    #pragma unroll
    for (int i = 0; i < 4; ++i) {
      int lin  = tid + i * 256;
      int row  = lin >> 3;
      int gsw  = lin & 7;
      int gsrc = gsw ^ (row & 7);
      int gr   = m0 + row;
      float f0, f1, f2, f3, f4, f5, f6, f7;
      if (d0 < 256) {
        const float4* p = (const float4*)(uu + (size_t)gr * LATENT + d0 + gsrc * 8);
        float4 A = p[0], Bv = p[1];
        f0 = A.x; f1 = A.y; f2 = A.z; f3 = A.w; f4 = Bv.x; f5 = Bv.y; f6 = Bv.z; f7 = Bv.w;
      } else if (d0 < 1280) {
        const float4* p = (const float4*)(cond + (size_t)gr * CONDD + (d0 - 256) + gsrc * 8);
        float4 A = p[0], Bv = p[1];
        f0 = A.x; f1 = A.y; f2 = A.z; f3 = A.w; f4 = Bv.x; f5 = Bv.y; f6 = Bv.z; f7 = Bv.w;
      } else {
        float tv = tau[gr];
        f0 = (gsrc == 0) ? tv : 0.f;
        f1 = f2 = f3 = f4 = f5 = f6 = f7 = 0.f;
      }
      u32x4 pk;
      pk[0] = (uint32_t)f2bf(f0) | ((uint32_t)f2bf(f1) << 16);
      pk[1] = (uint32_t)f2bf(f2) | ((uint32_t)f2bf(f3) << 16);
      pk[2] = (uint32_t)f2bf(f4) | ((uint32_t)f2bf(f5) << 16);
      pk[3] = (uint32_t)f2bf(f6) | ((uint32_t)f2bf(f7) << 16);
      *(u32x4*)(&sm.s.As[row * 64 + gsw * 8]) = pk;
    }
    {
      int rloc = lane >> 3;
      int gsw  = lane & 7;
      int gsrc = gsw ^ rloc;
      #pragma unroll
      for (int i = 0; i < 4; ++i) {
        int rbase = (wave * 4 + i) * 8;
        async16(w1k + (size_t)(rbase + rloc) * EINP + d0 + gsrc * 8,
                &sm.s.Bs[rbase * 64]);
      }
    }
    __syncthreads();
    #pragma unroll
    for (int ks = 0; ks < 2; ++ks) {
      short8 a[4], b[4];
      #pragma unroll
      for (int m = 0; m < 4; ++m) {
        int r = wm * 64 + m * 16 + ln;
        int g = (ks * 4 + q) ^ (r & 7);
        a[m] = *(const short8*)(&sm.s.As[r * 64 + g * 8]);
      }
      #pragma unroll
      for (int n = 0; n < 4; ++n) {
        int c = wn * 64 + n * 16 + ln;
        int g = (ks * 4 + q) ^ (c & 7);
        b[n] = *(const short8*)(&sm.s.Bs[c * 64 + g * 8]);
      }
      #pragma unroll
      for (int m = 0; m < 4; ++m)
        #pragma unroll
        for (int n = 0; n < 4; ++n)
          acc[m][n] = __builtin_amdgcn_mfma_f32_16x16x32_bf16(a[m], b[n], acc[m][n], 0, 0, 0);
    }
    __syncthreads();
  }

  #pragma unroll 1
  for (int hf = 0; hf < 2; ++hf) {
    if (wn == hf) {
      #pragma unroll
      for (int n = 0; n < 4; ++n) {
        int cl = n * 16 + ln;
        float bv = b1[n0 + hf * 64 + cl];
        #pragma unroll
        for (int m = 0; m < 4; ++m)
          #pragma unroll
          for (int r = 0; r < 4; ++r)
            sm.Cs[(wm * 64 + m * 16 + q * 4 + r) * 72 + cl] = f2bf(silu(acc[m][n][r] + bv));
      }
    }
    __syncthreads();
    #pragma unroll
    for (int i = 0; i < 4; ++i) {
      int lin = tid + i * 256;
      int row = lin >> 3;
      int grp = lin & 7;
      *(u32x4*)(H1 + (size_t)(m0 + row) * NTOT + n0 + hf * 64 + grp * 8) =
          *(const u32x4*)(&sm.Cs[row * 72 + grp * 8]);
    }
    __syncthreads();
  }
}

__global__ __launch_bounds__(256, 4)
void h2_gemm(u16* __restrict__ H, const float* __restrict__ p_hat,
             const u16* __restrict__ W2t, const float* __restrict__ b2) {
  __shared__ struct {
    union { struct { u16 As[128 * 64]; u16 Bs[128 * 64]; } s; u16 Cs[128 * 72]; } u;
    float Ps[128];
  } sm;

  const int tid  = threadIdx.x;
  const int wave = tid >> 6;
  const int lane = tid & 63;
  const int q    = lane >> 4;
  const int ln   = lane & 15;
  const int wm   = wave >> 1, wn = wave & 1;
  const int mt   = blockIdx.x >> 3;
  const int e    = blockIdx.x & 7;
  const int row0 = mt * 128;

  if (tid < 128) sm.Ps[tid] = p_hat[(size_t)(row0 + tid) * KEXP + e];

  const u16* w2k = W2t + (size_t)e * HID * HID;
  u16* hb = H + (size_t)row0 * NTOT + e * HID;

  const f32x4 fz = {0.f, 0.f, 0.f, 0.f};
  f32x4 acc[4][4];
  #pragma unroll
  for (int m = 0; m < 4; ++m)
    #pragma unroll
    for (int n = 0; n < 4; ++n) acc[m][n] = fz;

  const int rloc = lane >> 3;
  const int gsw  = lane & 7;
  const int gsrc = gsw ^ rloc;

  #pragma unroll 1
  for (int kc = 0; kc < 2; ++kc) {
    #pragma unroll
    for (int i = 0; i < 4; ++i) {
      int rbase = (wave * 4 + i) * 8;
      async16(hb + (size_t)(rbase + rloc) * NTOT + kc * 64 + gsrc * 8,
              &sm.u.s.As[rbase * 64]);
      async16(w2k + (size_t)(rbase + rloc) * HID + kc * 64 + gsrc * 8,
              &sm.u.s.Bs[rbase * 64]);
    }
    __syncthreads();
    #pragma unroll
    for (int ks = 0; ks < 2; ++ks) {
      short8 a[4], b[4];
      #pragma unroll
      for (int m = 0; m < 4; ++m) {
        int r = wm * 64 + m * 16 + ln;
        int g = (ks * 4 + q) ^ (r & 7);
        a[m] = *(const short8*)(&sm.u.s.As[r * 64 + g * 8]);
      }
      #pragma unroll
      for (int n = 0; n < 4; ++n) {
        int c = wn * 64 + n * 16 + ln;
        int g = (ks * 4 + q) ^ (c & 7);
        b[n] = *(const short8*)(&sm.u.s.Bs[c * 64 + g * 8]);
      }
      #pragma unroll
      for (int m = 0; m < 4; ++m)
        #pragma unroll
        for (int n = 0; n < 4; ++n)
          acc[m][n] = __builtin_amdgcn_mfma_f32_16x16x32_bf16(a[m], b[n], acc[m][n], 0, 0, 0);
    }
    __syncthreads();
  }

  #pragma unroll 1
  for (int hf = 0; hf < 2; ++hf) {
    if (wn == hf) {
      #pragma unroll
      for (int n = 0; n < 4; ++n) {
        int cl = n * 16 + ln;
        float bv = b2[e * HID + hf * 64 + cl];
        #pragma unroll
        for (int m = 0; m < 4; ++m)
          #pragma unroll
          for (int r = 0; r < 4; ++r) {
            int row = wm * 64 + m * 16 + q * 4 + r;
            sm.u.Cs[row * 72 + cl] = f2bf(sm.Ps[row] * silu(acc[m][n][r] + bv));
          }
      }
    }
    __syncthreads();
    #pragma unroll
    for (int i = 0; i < 4; ++i) {
      int lin = tid + i * 256;
      int row = lin >> 3;
      int grp = lin & 7;
      *(u32x4*)(hb + (size_t)row * NTOT + hf * 64 + grp * 8) =
          *(const u32x4*)(&sm.u.Cs[row * 72 + grp * 8]);
    }
    __syncthreads();
  }
}

extern "C" void kernel_launch(void* const* d_in, const int* in_sizes, int n_in,
                              void* d_out, int out_size, void* d_ws, size_t ws_size,
                              hipStream_t stream) {
  const float* cond  = (const float*)d_in[0];
  const float* u     = (const float*)d_in[1];
  const float* tau   = (const float*)d_in[2];
  const float* p_hat = (const float*)d_in[3];
  const float* W1    = (const float*)d_in[4];
  const float* b1    = (const float*)d_in[5];
  const float* W2    = (const float*)d_in[6];
  const float* b2    = (const float*)d_in[7];
  const float* W3    = (const float*)d_in[8];
  const float* b3    = (const float*)d_in[9];
  float* out = (float*)d_out;

  const size_t N1 = (size_t)KEXP * HID * EINP;    // 1,376,256
  const size_t N2 = (size_t)KEXP * HID * HID;     //   131,072
  const size_t N3 = (size_t)LATENT * NTOT;        //   262,144
  const size_t NH = (size_t)BROWS * NTOT;         // 33,554,432
  const size_t NX = (size_t)BROWS * EINP;         // 44,040,192 (bf16 X)

  u16* W1t  = (u16*)d_ws;
  u16* W2t  = W1t + N1;
  u16* W3t2 = W2t + N2;
  u16* H    = W3t2 + N3;

  if (ws_size >= (N1 + N2 + N3 + NH + NX) * sizeof(u16)) {
    // ---- fast path: merged prep + pipelined fused h1+h2 + pipelined out ----
    u16* Xbf = H + NH;
    prep<<<WCONV_TILES + XBLK, 256, 0, stream>>>(W1, W2, W3, cond, u, tau,
                                                 W1t, W2t, W3t2, Xbf);
    h1_fused<<<2048, 256, 0, stream>>>(Xbf, W1t, b1, W2t, b2, p_hat, H);
    out_gemm<<<1024, 256, 0, stream>>>(H, p_hat, W3t2, b3, out);
  } else if (ws_size >= (N1 + N2 + N3 + NH) * sizeof(u16)) {
    // ---- fallback: previous-session path (conv only, separate kernels) ----
    prep<<<WCONV_TILES, 256, 0, stream>>>(W1, W2, W3, cond, u, tau,
                                          W1t, W2t, W3t2, (u16*)nullptr);
    h1_gemm<<<2048, 256, 0, stream>>>(cond, u, tau, W1t, b1, H);
    h2_gemm<<<2048, 256, 0, stream>>>(H, p_hat, W2t, b2);
    out_gemm<<<1024, 256, 0, stream>>>(H, p_hat, W3t2, b3, out);
  }
}

// Round 6
// 403.723 us; speedup vs baseline: 1.3201x; 1.0694x over previous
//
#include <hip/hip_runtime.h>
#include <stdint.h>

typedef unsigned short u16;
typedef __attribute__((ext_vector_type(8))) short short8;   // 8 x bf16 MFMA operand
typedef __attribute__((ext_vector_type(4))) float f32x4;    // MFMA accumulator
typedef __attribute__((ext_vector_type(4))) uint32_t u32x4;

#define KEXP   8
#define LATENT 256
#define CONDD  1024
#define HID    128
#define EIN    1281
#define EINP   1344   // 21*64, zero padded
#define NCH    21
#define NTOT   1024   // KEXP*HID
#define BROWS  32768

__device__ __forceinline__ u16 f2bf(float x) {              // RNE fp32->bf16
  uint32_t v = __float_as_uint(x);
  v += 0x7fffu + ((v >> 16) & 1u);
  return (u16)(v >> 16);
}

__device__ __forceinline__ void async16(const void* g, void* l) {
  __builtin_amdgcn_global_load_lds(
      (const __attribute__((address_space(1))) void*)g,
      (__attribute__((address_space(3))) void*)l, 16, 0, 0);
}

__device__ __forceinline__ float silu(float x) { return x / (1.f + __expf(-x)); }

// ---------------------------------------------------------------------------
// prep: merged conv_w (1728 blocks) + x_conv (21504 blocks), one launch.
// ---------------------------------------------------------------------------
#define W1_TILES (KEXP * 42 * 4)    // 1344
#define W2_TILES (KEXP * 4 * 4)     // 128
#define W3_TILES (KEXP * 4 * 8)     // 256
#define WCONV_TILES (W1_TILES + W2_TILES + W3_TILES)   // 1728
#define XGRP (BROWS * 168)
#define XBLK (XGRP / 256)           // 21504

__global__ __launch_bounds__(256)
void prep(const float* __restrict__ W1, const float* __restrict__ W2,
          const float* __restrict__ W3, const float* __restrict__ cond,
          const float* __restrict__ uu, const float* __restrict__ tau,
          u16* __restrict__ W1t, u16* __restrict__ W2t, u16* __restrict__ W3t2,
          u16* __restrict__ Xbf) {
  __shared__ float t[32][33];
  const int bid = blockIdx.x;
  if (bid >= WCONV_TILES) {
    // ---- x_conv path ----
    int g = (bid - WCONV_TILES) * 256 + threadIdx.x;
    int row = g / 168;
    int c8  = g - row * 168;
    float f0 = 0.f, f1 = 0.f, f2 = 0.f, f3 = 0.f, f4 = 0.f, f5 = 0.f, f6 = 0.f, f7 = 0.f;
    if (c8 < 32) {
      const float4* p = (const float4*)(uu + (size_t)row * LATENT + c8 * 8);
      float4 a = p[0], b = p[1];
      f0 = a.x; f1 = a.y; f2 = a.z; f3 = a.w; f4 = b.x; f5 = b.y; f6 = b.z; f7 = b.w;
    } else if (c8 < 160) {
      const float4* p = (const float4*)(cond + (size_t)row * CONDD + (c8 - 32) * 8);
      float4 a = p[0], b = p[1];
      f0 = a.x; f1 = a.y; f2 = a.z; f3 = a.w; f4 = b.x; f5 = b.y; f6 = b.z; f7 = b.w;
    } else if (c8 == 160) {
      f0 = tau[row];                       // col 1280; 1281.. zero
    }
    u32x4 pk;
    pk[0] = (uint32_t)f2bf(f0) | ((uint32_t)f2bf(f1) << 16);
    pk[1] = (uint32_t)f2bf(f2) | ((uint32_t)f2bf(f3) << 16);
    pk[2] = (uint32_t)f2bf(f4) | ((uint32_t)f2bf(f5) << 16);
    pk[3] = (uint32_t)f2bf(f6) | ((uint32_t)f2bf(f7) << 16);
    *(u32x4*)(Xbf + (size_t)row * EINP + c8 * 8) = pk;
    return;
  }
  // ---- conv_w path ----
  const int tx = threadIdx.x & 31, ty = threadIdx.x >> 5;   // 32 x 8
  if (bid < W1_TILES) {
    int k = bid / 168, r = bid % 168;
    int d0 = (r / 4) * 32, h0 = (r % 4) * 32;
    const float* src = W1 + (size_t)k * EIN * HID;
    #pragma unroll
    for (int s = 0; s < 4; ++s) {
      int d = d0 + ty + s * 8;
      t[ty + s * 8][tx] = (d < EIN) ? src[(size_t)d * HID + h0 + tx] : 0.f;
    }
    __syncthreads();
    u16* dst = W1t + (size_t)k * HID * EINP;
    #pragma unroll
    for (int s = 0; s < 4; ++s)
      dst[(size_t)(h0 + ty + s * 8) * EINP + d0 + tx] = f2bf(t[tx][ty + s * 8]);
  } else if (bid < W1_TILES + W2_TILES) {
    int j = bid - W1_TILES;
    int k = j / 16, r = j % 16;
    int d0 = (r / 4) * 32, h0 = (r % 4) * 32;
    const float* src = W2 + (size_t)k * HID * HID;
    #pragma unroll
    for (int s = 0; s < 4; ++s)
      t[ty + s * 8][tx] = src[(size_t)(d0 + ty + s * 8) * HID + h0 + tx];
    __syncthreads();
    u16* dst = W2t + (size_t)k * HID * HID;
    #pragma unroll
    for (int s = 0; s < 4; ++s)
      dst[(size_t)(h0 + ty + s * 8) * HID + d0 + tx] = f2bf(t[tx][ty + s * 8]);
  } else {
    int j = bid - W1_TILES - W2_TILES;
    int k = j / 32, r = j % 32;
    int d0 = (r / 8) * 32, h0 = (r % 8) * 32;   // d=g (128), h=l (256)
    const float* src = W3 + (size_t)k * HID * LATENT;
    #pragma unroll
    for (int s = 0; s < 4; ++s)
      t[ty + s * 8][tx] = src[(size_t)(d0 + ty + s * 8) * LATENT + h0 + tx];
    __syncthreads();
    #pragma unroll
    for (int s = 0; s < 4; ++s)
      W3t2[(size_t)(h0 + ty + s * 8) * NTOT + k * HID + d0 + tx] = f2bf(t[tx][ty + s * 8]);
  }
}

// ---------------------------------------------------------------------------
// h1_fused: H[:, e*128:] = p[:,e] * silu( silu(X@W1t[e]+b1) @ W2t[e] + b2 ).
// Depth-2 prefetch for A (Xbf, HBM-stream): As[3].  Depth-1 for B (W1t,
// L2-resident): Bs[2].  Steady-state s_waitcnt vmcnt(4) (only the depth-2 A
// loads stay in flight across the barrier).  LDS = 80 KB -> 2 blk/CU.
// p-gate in registers (no LDS Ps).
// ---------------------------------------------------------------------------
__global__ __launch_bounds__(256, 2)
void h1_fused(const u16* __restrict__ Xbf, const u16* __restrict__ W1t,
              const float* __restrict__ b1, const u16* __restrict__ W2t,
              const float* __restrict__ b2, const float* __restrict__ p_hat,
              u16* __restrict__ H) {
  __shared__ union {
    struct { u16 As[3][8192]; u16 Bs[2][8192]; } s;   // 80 KB staging
    struct { u16 As2[16384]; u16 Bs2[2][8192]; } g;   // 64 KB GEMM2
    u16 Cs[128 * 72];                                 // 18 KB epilogue
  } sm;

  const int tid  = threadIdx.x;
  const int wave = tid >> 6;
  const int lane = tid & 63;
  const int q    = lane >> 4;
  const int ln   = lane & 15;
  const int wm   = wave >> 1, wn = wave & 1;
  const int bid  = blockIdx.x;
  const int mt   = ((bid >> 6) << 3) | (bid & 7);   // 0..255, same-XCD siblings
  const int e    = (bid >> 3) & 7;                  // expert
  const int m0   = mt * 128;
  const u16* w1k = W1t + (size_t)e * HID * EINP;
  const u16* xtb = Xbf + (size_t)m0 * EINP;

  const f32x4 fz = {0.f, 0.f, 0.f, 0.f};
  f32x4 acc[4][4];
  #pragma unroll
  for (int m = 0; m < 4; ++m)
    #pragma unroll
    for (int n = 0; n < 4; ++n) acc[m][n] = fz;

  const int rloc = lane >> 3;
  const int gsw  = lane & 7;
  const int gsrc = gsw ^ rloc;      // pre-swizzled global source, linear LDS dest

#define H1_SA(d0, buf) { \
  _Pragma("unroll") \
  for (int i_ = 0; i_ < 4; ++i_) { \
    int rb_ = (wave * 4 + i_) * 8; \
    async16(xtb + (size_t)(rb_ + rloc) * EINP + (d0) + gsrc * 8, &sm.s.As[buf][rb_ * 64]); \
  } }
#define H1_SB(d0, buf) { \
  _Pragma("unroll") \
  for (int i_ = 0; i_ < 4; ++i_) { \
    int rb_ = (wave * 4 + i_) * 8; \
    async16(w1k + (size_t)(rb_ + rloc) * EINP + (d0) + gsrc * 8, &sm.s.Bs[buf][rb_ * 64]); \
  } }

  auto mfma_chunk = [&](const u16* Ab, const u16* Bb) {
    __builtin_amdgcn_s_setprio(1);
    #pragma unroll
    for (int ks = 0; ks < 2; ++ks) {
      short8 a[4], b[4];
      #pragma unroll
      for (int m = 0; m < 4; ++m) {
        int r = wm * 64 + m * 16 + ln;
        int g = (ks * 4 + q) ^ (r & 7);
        a[m] = *(const short8*)(&Ab[r * 64 + g * 8]);
      }
      #pragma unroll
      for (int n = 0; n < 4; ++n) {
        int c = wn * 64 + n * 16 + ln;
        int g = (ks * 4 + q) ^ (c & 7);
        b[n] = *(const short8*)(&Bb[c * 64 + g * 8]);
      }
      #pragma unroll
      for (int m = 0; m < 4; ++m)
        #pragma unroll
        for (int n = 0; n < 4; ++n)
          acc[m][n] = __builtin_amdgcn_mfma_f32_16x16x32_bf16(a[m], b[n], acc[m][n], 0, 0, 0);
    }
    __builtin_amdgcn_s_setprio(0);
  };

// chunk t: compute (ac,bc); prefetch B(t+1)->bp (depth 1), A(t+2)->ap (depth 2)
#define H1_CH(trel, ac, bc, bp, ap, vm) \
  H1_SB(db + ((trel) + 1) * 64, bp); \
  H1_SA(db + ((trel) + 2) * 64, ap); \
  mfma_chunk(sm.s.As[ac], sm.s.Bs[bc]); \
  asm volatile("s_waitcnt vmcnt(" #vm ")" ::: "memory"); \
  __builtin_amdgcn_s_barrier(); \
  __builtin_amdgcn_sched_barrier(0);

  // ---------------- GEMM1: X @ W1t, K = 1344 = 21 chunks ----------------
  // prologue: A0->a0, B0->b0, A1->a1; wait A0,B0 (A1 stays in flight)
  H1_SA(0, 0); H1_SB(0, 0); H1_SA(64, 1);
  asm volatile("s_waitcnt vmcnt(4)" ::: "memory");
  __builtin_amdgcn_s_barrier();
  __builtin_amdgcn_sched_barrier(0);

  // t = 0..17: a = t%3, b = t%2 -> 6-chunk pattern, 3 iterations
  #pragma unroll 1
  for (int j = 0; j < 3; ++j) {
    const int db = j * 384;
    H1_CH(0, 0, 0, 1, 2, 4)
    H1_CH(1, 1, 1, 0, 0, 4)
    H1_CH(2, 2, 0, 1, 1, 4)
    H1_CH(3, 0, 1, 0, 2, 4)
    H1_CH(4, 1, 0, 1, 0, 4)
    H1_CH(5, 2, 1, 0, 1, 4)
  }
  // tail: t = 18,19,20
  {
    const int db = 1152;
    H1_CH(0, 0, 0, 1, 2, 4)            // t=18: B(19)->b1, A(20)->a2
    H1_SB(db + 128, 0);                // t=19: B(20)->b0 only
    mfma_chunk(sm.s.As[1], sm.s.Bs[1]);
    asm volatile("s_waitcnt vmcnt(0)" ::: "memory");
    __builtin_amdgcn_s_barrier();
    __builtin_amdgcn_sched_barrier(0);
    mfma_chunk(sm.s.As[2], sm.s.Bs[0]); // t=20
  }
  __syncthreads();   // all staging reads done before aliased LDS overlay

  // ---------------- fused GEMM2: silu(acc+b1) @ W2t[e], K = 128 ----------------
  const u16* w2k = W2t + (size_t)e * HID * HID;
  // prefetch BOTH W2 chunks under the As2-write phase
  #pragma unroll
  for (int kc = 0; kc < 2; ++kc)
    #pragma unroll
    for (int i = 0; i < 4; ++i) {
      int rbase = (wave * 4 + i) * 8;
      async16(w2k + (size_t)(rbase + rloc) * HID + kc * 64 + gsrc * 8,
              &sm.g.Bs2[kc][rbase * 64]);
    }

  // p-gate into registers (L2-hot; hidden behind GEMM2)
  float pr[4][4];
  #pragma unroll
  for (int m = 0; m < 4; ++m)
    #pragma unroll
    for (int r = 0; r < 4; ++r)
      pr[m][r] = p_hat[(size_t)(m0 + wm * 64 + m * 16 + q * 4 + r) * KEXP + e];

  // Write the full 128x128 H1 tile as bf16 into As2, XOR-swizzled:
  // element (row,h) at As2[row*128 + ((h>>3)^(row&7))*8 + (h&7)]
  #pragma unroll
  for (int n = 0; n < 4; ++n) {
    int cl = wn * 64 + n * 16 + ln;            // h = 0..127
    float bv = b1[e * HID + cl];
    #pragma unroll
    for (int m = 0; m < 4; ++m)
      #pragma unroll
      for (int r = 0; r < 4; ++r) {
        int row = wm * 64 + m * 16 + q * 4 + r;
        sm.g.As2[row * 128 + (((cl >> 3) ^ (row & 7)) << 3) + (cl & 7)] =
            f2bf(silu(acc[m][n][r] + bv));
      }
  }

  f32x4 acc2[4][4];
  #pragma unroll
  for (int m = 0; m < 4; ++m)
    #pragma unroll
    for (int n = 0; n < 4; ++n) acc2[m][n] = fz;

  __syncthreads();   // As2 ds_writes visible + both Bs2 DMAs landed (full drain)

  #pragma unroll
  for (int kc = 0; kc < 2; ++kc) {
    #pragma unroll
    for (int ks = 0; ks < 2; ++ks) {
      short8 a[4], b[4];
      #pragma unroll
      for (int m = 0; m < 4; ++m) {
        int r = wm * 64 + m * 16 + ln;
        int G = kc * 8 + ks * 4 + q;           // 4-bit h-group
        int g = (G & 8) | ((G ^ (r & 7)) & 7);
        a[m] = *(const short8*)(&sm.g.As2[r * 128 + g * 8]);
      }
      #pragma unroll
      for (int n = 0; n < 4; ++n) {
        int c = wn * 64 + n * 16 + ln;
        int g = (ks * 4 + q) ^ (c & 7);
        b[n] = *(const short8*)(&sm.g.Bs2[kc][c * 64 + g * 8]);
      }
      #pragma unroll
      for (int m = 0; m < 4; ++m)
        #pragma unroll
        for (int n = 0; n < 4; ++n)
          acc2[m][n] = __builtin_amdgcn_mfma_f32_16x16x32_bf16(a[m], b[n], acc2[m][n], 0, 0, 0);
    }
  }
  __syncthreads();

  // ---------------- epilogue: p * silu(acc2 + b2) -> bf16 H, coalesced ----------------
  u16* hb = H + (size_t)m0 * NTOT + e * HID;
  #pragma unroll 1
  for (int hf = 0; hf < 2; ++hf) {
    if (wn == hf) {
      #pragma unroll
      for (int n = 0; n < 4; ++n) {
        int cl = n * 16 + ln;
        float bv = b2[e * HID + hf * 64 + cl];
        #pragma unroll
        for (int m = 0; m < 4; ++m)
          #pragma unroll
          for (int r = 0; r < 4; ++r) {
            int row = wm * 64 + m * 16 + q * 4 + r;
            sm.Cs[row * 72 + cl] = f2bf(pr[m][r] * silu(acc2[m][n][r] + bv));
          }
      }
    }
    __syncthreads();
    #pragma unroll
    for (int i = 0; i < 4; ++i) {
      int lin = tid + i * 256;
      int row = lin >> 3;
      int grp = lin & 7;
      *(u32x4*)(hb + (size_t)row * NTOT + hf * 64 + grp * 8) =
          *(const u32x4*)(&sm.Cs[row * 72 + grp * 8]);
    }
    __syncthreads();
  }
#undef H1_SA
#undef H1_SB
#undef H1_CH
}

// ---------------------------------------------------------------------------
// out_gemm: out = Hg @ W3t2^T + (p @ b3). M=32768 N=256 K=1024, 16 chunks.
// Depth-2 prefetch for BOTH operands: As[3]/Bs[3], steady vmcnt(6).
// 78 KB LDS -> 2 blk/CU.
// ---------------------------------------------------------------------------
__global__ __launch_bounds__(256, 2)
void out_gemm(const u16* __restrict__ H, const float* __restrict__ p_hat,
              const u16* __restrict__ W3t2, const float* __restrict__ b3,
              float* __restrict__ out) {
  __shared__ struct {
    u16 As[3][4096];      // 24 KB (64 x 64 each)
    u16 Bs[3][8192];      // 48 KB (128 x 64 each)
    float Ps[64 * 8];     // 2 KB
    float B3s[128 * 8];   // 4 KB
  } sm;

  const int tid  = threadIdx.x;
  const int wave = tid >> 6;
  const int lane = tid & 63;
  const int q    = lane >> 4;
  const int ln   = lane & 15;
  const int bid  = blockIdx.x;
  const int mt   = ((bid >> 4) << 3) | (bid & 7);   // 0..511
  const int bn   = (bid >> 3) & 1;
  const int m0   = mt * 64, n0 = bn * 128;

  // stage p rows (64 x 8) and b3 columns (128 x 8, transposed)
  if (tid < 128) {
    int row = tid >> 1, h = tid & 1;
    *(float4*)(&sm.Ps[row * 8 + h * 4]) = *(const float4*)(p_hat + (size_t)(m0 + row) * KEXP + h * 4);
  }
  #pragma unroll
  for (int i = 0; i < 4; ++i) {
    int k = i * 2 + (tid >> 7);
    int c = tid & 127;
    sm.B3s[c * 8 + k] = b3[k * LATENT + n0 + c];
  }

  const f32x4 fz = {0.f, 0.f, 0.f, 0.f};
  f32x4 acc[4][2];
  #pragma unroll
  for (int m = 0; m < 4; ++m) { acc[m][0] = fz; acc[m][1] = fz; }

  const int rloc = lane >> 3;
  const int gsw  = lane & 7;
  const int gsrc = gsw ^ rloc;

#define OG_SA(d0, buf) { \
  _Pragma("unroll") \
  for (int i_ = 0; i_ < 2; ++i_) { \
    int rb_ = (wave * 2 + i_) * 8; \
    async16(H + (size_t)(m0 + rb_ + rloc) * NTOT + (d0) + gsrc * 8, &sm.As[buf][rb_ * 64]); \
  } }
#define OG_SB(d0, buf) { \
  _Pragma("unroll") \
  for (int i_ = 0; i_ < 4; ++i_) { \
    int rb_ = (wave * 4 + i_) * 8; \
    async16(W3t2 + (size_t)(n0 + rb_ + rloc) * NTOT + (d0) + gsrc * 8, &sm.Bs[buf][rb_ * 64]); \
  } }

  auto mfma_chunk = [&](const u16* Ab, const u16* Bb) {
    __builtin_amdgcn_s_setprio(1);
    #pragma unroll
    for (int ks = 0; ks < 2; ++ks) {
      short8 a[4], b[2];
      #pragma unroll
      for (int m = 0; m < 4; ++m) {
        int r = m * 16 + ln;
        int g = (ks * 4 + q) ^ (r & 7);
        a[m] = *(const short8*)(&Ab[r * 64 + g * 8]);
      }
      #pragma unroll
      for (int n = 0; n < 2; ++n) {
        int c = wave * 32 + n * 16 + ln;
        int g = (ks * 4 + q) ^ (c & 7);
        b[n] = *(const short8*)(&Bb[c * 64 + g * 8]);
      }
      #pragma unroll
      for (int m = 0; m < 4; ++m)
        #pragma unroll
        for (int n = 0; n < 2; ++n)
          acc[m][n] = __builtin_amdgcn_mfma_f32_16x16x32_bf16(a[m], b[n], acc[m][n], 0, 0, 0);
    }
    __builtin_amdgcn_s_setprio(0);
  };

// chunk t: compute buffer ac = t%3; prefetch A/B(t+2) -> ap = (t+2)%3
#define OG_CH(trel, ac, ap) \
  OG_SB(db + ((trel) + 2) * 64, ap); \
  OG_SA(db + ((trel) + 2) * 64, ap); \
  mfma_chunk(sm.As[ac], sm.Bs[ac]); \
  asm volatile("s_waitcnt vmcnt(6)" ::: "memory"); \
  __builtin_amdgcn_s_barrier(); \
  __builtin_amdgcn_sched_barrier(0);

  // prologue: chunks 0,1 staged; wait chunk 0 (chunk 1's 6 loads in flight)
  OG_SA(0, 0); OG_SB(0, 0);
  OG_SA(64, 1); OG_SB(64, 1);
  asm volatile("s_waitcnt vmcnt(6)" ::: "memory");
  __builtin_amdgcn_s_barrier();
  __builtin_amdgcn_sched_barrier(0);

  // t = 0..11: buffer pattern period 3, 3-chunk macro x4
  #pragma unroll 1
  for (int j = 0; j < 4; ++j) {
    const int db = j * 192;
    OG_CH(0, 0, 2)
    OG_CH(1, 1, 0)
    OG_CH(2, 2, 1)
  }
  // tail: t = 12..15
  {
    const int db = 768;
    OG_CH(0, 0, 2)                      // t=12: stage 14 -> a2
    OG_CH(1, 1, 0)                      // t=13: stage 15 -> a0
    mfma_chunk(sm.As[2], sm.Bs[2]);     // t=14
    asm volatile("s_waitcnt vmcnt(0)" ::: "memory");
    __builtin_amdgcn_s_barrier();
    __builtin_amdgcn_sched_barrier(0);
    mfma_chunk(sm.As[0], sm.Bs[0]);     // t=15
  }

  // ---- epilogue: + sum_k p[row][k]*b3[k][col], fp32 store ----
  #pragma unroll
  for (int n = 0; n < 2; ++n) {
    int col = wave * 32 + n * 16 + ln;
    float4 c0 = *(const float4*)(&sm.B3s[col * 8]);
    float4 c1 = *(const float4*)(&sm.B3s[col * 8 + 4]);
    #pragma unroll
    for (int m = 0; m < 4; ++m)
      #pragma unroll
      for (int r = 0; r < 4; ++r) {
        int row = m * 16 + q * 4 + r;
        float4 p0 = *(const float4*)(&sm.Ps[row * 8]);
        float4 p1 = *(const float4*)(&sm.Ps[row * 8 + 4]);
        float v = acc[m][n][r]
                + p0.x * c0.x + p0.y * c0.y + p0.z * c0.z + p0.w * c0.w
                + p1.x * c1.x + p1.y * c1.y + p1.z * c1.z + p1.w * c1.w;
        out[(size_t)(m0 + row) * LATENT + n0 + col] = v;
      }
  }
#undef OG_SA
#undef OG_SB
#undef OG_CH
}

// ---------------------------------------------------------------------------
// FALLBACK PATH (only if ws_size too small for Xbf): previous-session
// h1_gemm + h2_gemm, verbatim.
// ---------------------------------------------------------------------------
__global__ __launch_bounds__(256, 4)
void h1_gemm(const float* __restrict__ cond, const float* __restrict__ uu,
             const float* __restrict__ tau, const u16* __restrict__ W1t,
             const float* __restrict__ b1, u16* __restrict__ H1) {
  __shared__ union {
    struct { u16 As[128 * 64]; u16 Bs[128 * 64]; } s;
    u16 Cs[128 * 72];
  } sm;

  const int tid  = threadIdx.x;
  const int wave = tid >> 6;
  const int lane = tid & 63;
  const int q    = lane >> 4;
  const int ln   = lane & 15;
  const int wm   = wave >> 1, wn = wave & 1;
  const int bid  = blockIdx.x;
  const int mt   = ((bid >> 6) << 3) | (bid & 7);
  const int e    = (bid >> 3) & 7;
  const int m0   = mt * 128, n0 = e * 128;
  const u16* w1k = W1t + (size_t)e * HID * EINP;

  const f32x4 fz = {0.f, 0.f, 0.f, 0.f};
  f32x4 acc[4][4];
  #pragma unroll
  for (int m = 0; m < 4; ++m)
    #pragma unroll
    for (int n = 0; n < 4; ++n) acc[m][n] = fz;

  #pragma unroll 1
  for (int ic = 0; ic < NCH; ++ic) {
    const int d0 = ic * 64;
    #pragma unroll
    for (int i = 0; i < 4; ++i) {
      int lin  = tid + i * 256;
      int row  = lin >> 3;
      int gsw  = lin & 7;
      int gsrc = gsw ^ (row & 7);
      int gr   = m0 + row;
      float f0, f1, f2, f3, f4, f5, f6, f7;
      if (d0 < 256) {
        const float4* p = (const float4*)(uu + (size_t)gr * LATENT + d0 + gsrc * 8);
        float4 A = p[0], Bv = p[1];
        f0 = A.x; f1 = A.y; f2 = A.z; f3 = A.w; f4 = Bv.x; f5 = Bv.y; f6 = Bv.z; f7 = Bv.w;
      } else if (d0 < 1280) {
        const float4* p = (const float4*)(cond + (size_t)gr * CONDD + (d0 - 256) + gsrc * 8);
        float4 A = p[0], Bv = p[1];
        f0 = A.x; f1 = A.y; f2 = A.z; f3 = A.w; f4 = Bv.x; f5 = Bv.y; f6 = Bv.z; f7 = Bv.w;
      } else {
        float tv = tau[gr];
        f0 = (gsrc == 0) ? tv : 0.f;
        f1 = f2 = f3 = f4 = f5 = f6 = f7 = 0.f;
      }
      u32x4 pk;
      pk[0] = (uint32_t)f2bf(f0) | ((uint32_t)f2bf(f1) << 16);
      pk[1] = (uint32_t)f2bf(f2) | ((uint32_t)f2bf(f3) << 16);
      pk[2] = (uint32_t)f2bf(f4) | ((uint32_t)f2bf(f5) << 16);
      pk[3] = (uint32_t)f2bf(f6) | ((uint32_t)f2bf(f7) << 16);
      *(u32x4*)(&sm.s.As[row * 64 + gsw * 8]) = pk;
    }
    {
      int rloc = lane >> 3;
      int gsw  = lane & 7;
      int gsrc = gsw ^ rloc;
      #pragma unroll
      for (int i = 0; i < 4; ++i) {
        int rbase = (wave * 4 + i) * 8;
        async16(w1k + (size_t)(rbase + rloc) * EINP + d0 + gsrc * 8,
                &sm.s.Bs[rbase * 64]);
      }
    }
    __syncthreads();
    #pragma unroll
    for (int ks = 0; ks < 2; ++ks) {
      short8 a[4], b[4];
      #pragma unroll
      for (int m = 0; m < 4; ++m) {
        int r = wm * 64 + m * 16 + ln;
        int g = (ks * 4 + q) ^ (r & 7);
        a[m] = *(const short8*)(&sm.s.As[r * 64 + g * 8]);
      }
      #pragma unroll
      for (int n = 0; n < 4; ++n) {
        int c = wn * 64 + n * 16 + ln;
        int g = (ks * 4 + q) ^ (c & 7);
        b[n] = *(const short8*)(&sm.s.Bs[c * 64 + g * 8]);
      }
      #pragma unroll
      for (int m = 0; m < 4; ++m)
        #pragma unroll
        for (int n = 0; n < 4; ++n)
          acc[m][n] = __builtin_amdgcn_mfma_f32_16x16x32_bf16(a[m], b[n], acc[m][n], 0, 0, 0);
    }
    __syncthreads();
  }

  #pragma unroll 1
  for (int hf = 0; hf < 2; ++hf) {
    if (wn == hf) {
      #pragma unroll
      for (int n = 0; n < 4; ++n) {
        int cl = n * 16 + ln;
        float bv = b1[n0 + hf * 64 + cl];
        #pragma unroll
        for (int m = 0; m < 4; ++m)
          #pragma unroll
          for (int r = 0; r < 4; ++r)
            sm.Cs[(wm * 64 + m * 16 + q * 4 + r) * 72 + cl] = f2bf(silu(acc[m][n][r] + bv));
      }
    }
    __syncthreads();
    #pragma unroll
    for (int i = 0; i < 4; ++i) {
      int lin = tid + i * 256;
      int row = lin >> 3;
      int grp = lin & 7;
      *(u32x4*)(H1 + (size_t)(m0 + row) * NTOT + n0 + hf * 64 + grp * 8) =
          *(const u32x4*)(&sm.Cs[row * 72 + grp * 8]);
    }
    __syncthreads();
  }
}

__global__ __launch_bounds__(256, 4)
void h2_gemm(u16* __restrict__ H, const float* __restrict__ p_hat,
             const u16* __restrict__ W2t, const float* __restrict__ b2) {
  __shared__ struct {
    union { struct { u16 As[128 * 64]; u16 Bs[128 * 64]; } s; u16 Cs[128 * 72]; } u;
    float Ps[128];
  } sm;

  const int tid  = threadIdx.x;
  const int wave = tid >> 6;
  const int lane = tid & 63;
  const int q    = lane >> 4;
  const int ln   = lane & 15;
  const int wm   = wave >> 1, wn = wave & 1;
  const int mt   = blockIdx.x >> 3;
  const int e    = blockIdx.x & 7;
  const int row0 = mt * 128;

  if (tid < 128) sm.Ps[tid] = p_hat[(size_t)(row0 + tid) * KEXP + e];

  const u16* w2k = W2t + (size_t)e * HID * HID;
  u16* hb = H + (size_t)row0 * NTOT + e * HID;

  const f32x4 fz = {0.f, 0.f, 0.f, 0.f};
  f32x4 acc[4][4];
  #pragma unroll
  for (int m = 0; m < 4; ++m)
    #pragma unroll
    for (int n = 0; n < 4; ++n) acc[m][n] = fz;

  const int rloc = lane >> 3;
  const int gsw  = lane & 7;
  const int gsrc = gsw ^ rloc;

  #pragma unroll 1
  for (int kc = 0; kc < 2; ++kc) {
    #pragma unroll
    for (int i = 0; i < 4; ++i) {
      int rbase = (wave * 4 + i) * 8;
      async16(hb + (size_t)(rbase + rloc) * NTOT + kc * 64 + gsrc * 8,
              &sm.u.s.As[rbase * 64]);
      async16(w2k + (size_t)(rbase + rloc) * HID + kc * 64 + gsrc * 8,
              &sm.u.s.Bs[rbase * 64]);
    }
    __syncthreads();
    #pragma unroll
    for (int ks = 0; ks < 2; ++ks) {
      short8 a[4], b[4];
      #pragma unroll
      for (int m = 0; m < 4; ++m) {
        int r = wm * 64 + m * 16 + ln;
        int g = (ks * 4 + q) ^ (r & 7);
        a[m] = *(const short8*)(&sm.u.s.As[r * 64 + g * 8]);
      }
      #pragma unroll
      for (int n = 0; n < 4; ++n) {
        int c = wn * 64 + n * 16 + ln;
        int g = (ks * 4 + q) ^ (c & 7);
        b[n] = *(const short8*)(&sm.u.s.Bs[c * 64 + g * 8]);
      }
      #pragma unroll
      for (int m = 0; m < 4; ++m)
        #pragma unroll
        for (int n = 0; n < 4; ++n)
          acc[m][n] = __builtin_amdgcn_mfma_f32_16x16x32_bf16(a[m], b[n], acc[m][n], 0, 0, 0);
    }
    __syncthreads();
  }

  #pragma unroll 1
  for (int hf = 0; hf < 2; ++hf) {
    if (wn == hf) {
      #pragma unroll
      for (int n = 0; n < 4; ++n) {
        int cl = n * 16 + ln;
        float bv = b2[e * HID + hf * 64 + cl];
        #pragma unroll
        for (int m = 0; m < 4; ++m)
          #pragma unroll
          for (int r = 0; r < 4; ++r) {
            int row = wm * 64 + m * 16 + q * 4 + r;
            sm.u.Cs[row * 72 + cl] = f2bf(sm.Ps[row] * silu(acc[m][n][r] + bv));
          }
      }
    }
    __syncthreads();
    #pragma unroll
    for (int i = 0; i < 4; ++i) {
      int lin = tid + i * 256;
      int row = lin >> 3;
      int grp = lin & 7;
      *(u32x4*)(hb + (size_t)row * NTOT + hf * 64 + grp * 8) =
          *(const u32x4*)(&sm.u.Cs[row * 72 + grp * 8]);
    }
    __syncthreads();
  }
}

extern "C" void kernel_launch(void* const* d_in, const int* in_sizes, int n_in,
                              void* d_out, int out_size, void* d_ws, size_t ws_size,
                              hipStream_t stream) {
  const float* cond  = (const float*)d_in[0];
  const float* u     = (const float*)d_in[1];
  const float* tau   = (const float*)d_in[2];
  const float* p_hat = (const float*)d_in[3];
  const float* W1    = (const float*)d_in[4];
  const float* b1    = (const float*)d_in[5];
  const float* W2    = (const float*)d_in[6];
  const float* b2    = (const float*)d_in[7];
  const float* W3    = (const float*)d_in[8];
  const float* b3    = (const float*)d_in[9];
  float* out = (float*)d_out;

  const size_t N1 = (size_t)KEXP * HID * EINP;    // 1,376,256
  const size_t N2 = (size_t)KEXP * HID * HID;     //   131,072
  const size_t N3 = (size_t)LATENT * NTOT;        //   262,144
  const size_t NH = (size_t)BROWS * NTOT;         // 33,554,432
  const size_t NX = (size_t)BROWS * EINP;         // 44,040,192 (bf16 X)

  u16* W1t  = (u16*)d_ws;
  u16* W2t  = W1t + N1;
  u16* W3t2 = W2t + N2;
  u16* H    = W3t2 + N3;

  if (ws_size >= (N1 + N2 + N3 + NH + NX) * sizeof(u16)) {
    // ---- fast path: merged prep + deep-pipelined fused h1+h2 + out ----
    u16* Xbf = H + NH;
    prep<<<WCONV_TILES + XBLK, 256, 0, stream>>>(W1, W2, W3, cond, u, tau,
                                                 W1t, W2t, W3t2, Xbf);
    h1_fused<<<2048, 256, 0, stream>>>(Xbf, W1t, b1, W2t, b2, p_hat, H);
    out_gemm<<<1024, 256, 0, stream>>>(H, p_hat, W3t2, b3, out);
  } else if (ws_size >= (N1 + N2 + N3 + NH) * sizeof(u16)) {
    // ---- fallback: previous-session path ----
    prep<<<WCONV_TILES, 256, 0, stream>>>(W1, W2, W3, cond, u, tau,
                                          W1t, W2t, W3t2, (u16*)nullptr);
    h1_gemm<<<2048, 256, 0, stream>>>(cond, u, tau, W1t, b1, H);
    h2_gemm<<<2048, 256, 0, stream>>>(H, p_hat, W2t, b2);
    out_gemm<<<1024, 256, 0, stream>>>(H, p_hat, W3t2, b3, out);
  }
}

// Round 7
// 395.181 us; speedup vs baseline: 1.3487x; 1.0216x over previous
//
#include <hip/hip_runtime.h>
#include <stdint.h>

typedef unsigned short u16;
typedef __attribute__((ext_vector_type(8))) short short8;   // 8 x bf16 MFMA operand
typedef __attribute__((ext_vector_type(4))) float f32x4;    // MFMA accumulator
typedef __attribute__((ext_vector_type(4))) uint32_t u32x4;

#define KEXP   8
#define LATENT 256
#define CONDD  1024
#define HID    128
#define EIN    1281
#define EINP   1344   // 21*64, zero padded
#define NCH    21
#define NTOT   1024   // KEXP*HID
#define BROWS  32768

__device__ __forceinline__ u16 f2bf(float x) {              // RNE fp32->bf16
  uint32_t v = __float_as_uint(x);
  v += 0x7fffu + ((v >> 16) & 1u);
  return (u16)(v >> 16);
}

__device__ __forceinline__ void async16(const void* g, void* l) {
  __builtin_amdgcn_global_load_lds(
      (const __attribute__((address_space(1))) void*)g,
      (__attribute__((address_space(3))) void*)l, 16, 0, 0);
}

__device__ __forceinline__ float silu(float x) { return x / (1.f + __expf(-x)); }

// ---------------------------------------------------------------------------
// prep: merged conv_w (1728 blocks) + x_conv (21504 blocks), one launch.
// (unchanged from round 6)
// ---------------------------------------------------------------------------
#define W1_TILES (KEXP * 42 * 4)    // 1344
#define W2_TILES (KEXP * 4 * 4)     // 128
#define W3_TILES (KEXP * 4 * 8)     // 256
#define WCONV_TILES (W1_TILES + W2_TILES + W3_TILES)   // 1728
#define XGRP (BROWS * 168)
#define XBLK (XGRP / 256)           // 21504

__global__ __launch_bounds__(256)
void prep(const float* __restrict__ W1, const float* __restrict__ W2,
          const float* __restrict__ W3, const float* __restrict__ cond,
          const float* __restrict__ uu, const float* __restrict__ tau,
          u16* __restrict__ W1t, u16* __restrict__ W2t, u16* __restrict__ W3t2,
          u16* __restrict__ Xbf) {
  __shared__ float t[32][33];
  const int bid = blockIdx.x;
  if (bid >= WCONV_TILES) {
    // ---- x_conv path ----
    int g = (bid - WCONV_TILES) * 256 + threadIdx.x;
    int row = g / 168;
    int c8  = g - row * 168;
    float f0 = 0.f, f1 = 0.f, f2 = 0.f, f3 = 0.f, f4 = 0.f, f5 = 0.f, f6 = 0.f, f7 = 0.f;
    if (c8 < 32) {
      const float4* p = (const float4*)(uu + (size_t)row * LATENT + c8 * 8);
      float4 a = p[0], b = p[1];
      f0 = a.x; f1 = a.y; f2 = a.z; f3 = a.w; f4 = b.x; f5 = b.y; f6 = b.z; f7 = b.w;
    } else if (c8 < 160) {
      const float4* p = (const float4*)(cond + (size_t)row * CONDD + (c8 - 32) * 8);
      float4 a = p[0], b = p[1];
      f0 = a.x; f1 = a.y; f2 = a.z; f3 = a.w; f4 = b.x; f5 = b.y; f6 = b.z; f7 = b.w;
    } else if (c8 == 160) {
      f0 = tau[row];                       // col 1280; 1281.. zero
    }
    u32x4 pk;
    pk[0] = (uint32_t)f2bf(f0) | ((uint32_t)f2bf(f1) << 16);
    pk[1] = (uint32_t)f2bf(f2) | ((uint32_t)f2bf(f3) << 16);
    pk[2] = (uint32_t)f2bf(f4) | ((uint32_t)f2bf(f5) << 16);
    pk[3] = (uint32_t)f2bf(f6) | ((uint32_t)f2bf(f7) << 16);
    *(u32x4*)(Xbf + (size_t)row * EINP + c8 * 8) = pk;
    return;
  }
  // ---- conv_w path ----
  const int tx = threadIdx.x & 31, ty = threadIdx.x >> 5;   // 32 x 8
  if (bid < W1_TILES) {
    int k = bid / 168, r = bid % 168;
    int d0 = (r / 4) * 32, h0 = (r % 4) * 32;
    const float* src = W1 + (size_t)k * EIN * HID;
    #pragma unroll
    for (int s = 0; s < 4; ++s) {
      int d = d0 + ty + s * 8;
      t[ty + s * 8][tx] = (d < EIN) ? src[(size_t)d * HID + h0 + tx] : 0.f;
    }
    __syncthreads();
    u16* dst = W1t + (size_t)k * HID * EINP;
    #pragma unroll
    for (int s = 0; s < 4; ++s)
      dst[(size_t)(h0 + ty + s * 8) * EINP + d0 + tx] = f2bf(t[tx][ty + s * 8]);
  } else if (bid < W1_TILES + W2_TILES) {
    int j = bid - W1_TILES;
    int k = j / 16, r = j % 16;
    int d0 = (r / 4) * 32, h0 = (r % 4) * 32;
    const float* src = W2 + (size_t)k * HID * HID;
    #pragma unroll
    for (int s = 0; s < 4; ++s)
      t[ty + s * 8][tx] = src[(size_t)(d0 + ty + s * 8) * HID + h0 + tx];
    __syncthreads();
    u16* dst = W2t + (size_t)k * HID * HID;
    #pragma unroll
    for (int s = 0; s < 4; ++s)
      dst[(size_t)(h0 + ty + s * 8) * HID + d0 + tx] = f2bf(t[tx][ty + s * 8]);
  } else {
    int j = bid - W1_TILES - W2_TILES;
    int k = j / 32, r = j % 32;
    int d0 = (r / 8) * 32, h0 = (r % 8) * 32;   // d=g (128), h=l (256)
    const float* src = W3 + (size_t)k * HID * LATENT;
    #pragma unroll
    for (int s = 0; s < 4; ++s)
      t[ty + s * 8][tx] = src[(size_t)(d0 + ty + s * 8) * LATENT + h0 + tx];
    __syncthreads();
    #pragma unroll
    for (int s = 0; s < 4; ++s)
      W3t2[(size_t)(h0 + ty + s * 8) * NTOT + k * HID + d0 + tx] = f2bf(t[tx][ty + s * 8]);
  }
}

// ---------------------------------------------------------------------------
// h1_fused (unchanged from round 6 — verified 146.5 us).
// ---------------------------------------------------------------------------
__global__ __launch_bounds__(256, 2)
void h1_fused(const u16* __restrict__ Xbf, const u16* __restrict__ W1t,
              const float* __restrict__ b1, const u16* __restrict__ W2t,
              const float* __restrict__ b2, const float* __restrict__ p_hat,
              u16* __restrict__ H) {
  __shared__ union {
    struct { u16 As[3][8192]; u16 Bs[2][8192]; } s;   // 80 KB staging
    struct { u16 As2[16384]; u16 Bs2[2][8192]; } g;   // 64 KB GEMM2
    u16 Cs[128 * 72];                                 // 18 KB epilogue
  } sm;

  const int tid  = threadIdx.x;
  const int wave = tid >> 6;
  const int lane = tid & 63;
  const int q    = lane >> 4;
  const int ln   = lane & 15;
  const int wm   = wave >> 1, wn = wave & 1;
  const int bid  = blockIdx.x;
  const int mt   = ((bid >> 6) << 3) | (bid & 7);   // 0..255, same-XCD siblings
  const int e    = (bid >> 3) & 7;                  // expert
  const int m0   = mt * 128;
  const u16* w1k = W1t + (size_t)e * HID * EINP;
  const u16* xtb = Xbf + (size_t)m0 * EINP;

  const f32x4 fz = {0.f, 0.f, 0.f, 0.f};
  f32x4 acc[4][4];
  #pragma unroll
  for (int m = 0; m < 4; ++m)
    #pragma unroll
    for (int n = 0; n < 4; ++n) acc[m][n] = fz;

  const int rloc = lane >> 3;
  const int gsw  = lane & 7;
  const int gsrc = gsw ^ rloc;      // pre-swizzled global source, linear LDS dest

#define H1_SA(d0, buf) { \
  _Pragma("unroll") \
  for (int i_ = 0; i_ < 4; ++i_) { \
    int rb_ = (wave * 4 + i_) * 8; \
    async16(xtb + (size_t)(rb_ + rloc) * EINP + (d0) + gsrc * 8, &sm.s.As[buf][rb_ * 64]); \
  } }
#define H1_SB(d0, buf) { \
  _Pragma("unroll") \
  for (int i_ = 0; i_ < 4; ++i_) { \
    int rb_ = (wave * 4 + i_) * 8; \
    async16(w1k + (size_t)(rb_ + rloc) * EINP + (d0) + gsrc * 8, &sm.s.Bs[buf][rb_ * 64]); \
  } }

  auto mfma_chunk = [&](const u16* Ab, const u16* Bb) {
    __builtin_amdgcn_s_setprio(1);
    #pragma unroll
    for (int ks = 0; ks < 2; ++ks) {
      short8 a[4], b[4];
      #pragma unroll
      for (int m = 0; m < 4; ++m) {
        int r = wm * 64 + m * 16 + ln;
        int g = (ks * 4 + q) ^ (r & 7);
        a[m] = *(const short8*)(&Ab[r * 64 + g * 8]);
      }
      #pragma unroll
      for (int n = 0; n < 4; ++n) {
        int c = wn * 64 + n * 16 + ln;
        int g = (ks * 4 + q) ^ (c & 7);
        b[n] = *(const short8*)(&Bb[c * 64 + g * 8]);
      }
      #pragma unroll
      for (int m = 0; m < 4; ++m)
        #pragma unroll
        for (int n = 0; n < 4; ++n)
          acc[m][n] = __builtin_amdgcn_mfma_f32_16x16x32_bf16(a[m], b[n], acc[m][n], 0, 0, 0);
    }
    __builtin_amdgcn_s_setprio(0);
  };

// chunk t: compute (ac,bc); prefetch B(t+1)->bp (depth 1), A(t+2)->ap (depth 2)
#define H1_CH(trel, ac, bc, bp, ap, vm) \
  H1_SB(db + ((trel) + 1) * 64, bp); \
  H1_SA(db + ((trel) + 2) * 64, ap); \
  mfma_chunk(sm.s.As[ac], sm.s.Bs[bc]); \
  asm volatile("s_waitcnt vmcnt(" #vm ")" ::: "memory"); \
  __builtin_amdgcn_s_barrier(); \
  __builtin_amdgcn_sched_barrier(0);

  // ---------------- GEMM1: X @ W1t, K = 1344 = 21 chunks ----------------
  // prologue: A0->a0, B0->b0, A1->a1; wait A0,B0 (A1 stays in flight)
  H1_SA(0, 0); H1_SB(0, 0); H1_SA(64, 1);
  asm volatile("s_waitcnt vmcnt(4)" ::: "memory");
  __builtin_amdgcn_s_barrier();
  __builtin_amdgcn_sched_barrier(0);

  // t = 0..17: a = t%3, b = t%2 -> 6-chunk pattern, 3 iterations
  #pragma unroll 1
  for (int j = 0; j < 3; ++j) {
    const int db = j * 384;
    H1_CH(0, 0, 0, 1, 2, 4)
    H1_CH(1, 1, 1, 0, 0, 4)
    H1_CH(2, 2, 0, 1, 1, 4)
    H1_CH(3, 0, 1, 0, 2, 4)
    H1_CH(4, 1, 0, 1, 0, 4)
    H1_CH(5, 2, 1, 0, 1, 4)
  }
  // tail: t = 18,19,20
  {
    const int db = 1152;
    H1_CH(0, 0, 0, 1, 2, 4)            // t=18: B(19)->b1, A(20)->a2
    H1_SB(db + 128, 0);                // t=19: B(20)->b0 only
    mfma_chunk(sm.s.As[1], sm.s.Bs[1]);
    asm volatile("s_waitcnt vmcnt(0)" ::: "memory");
    __builtin_amdgcn_s_barrier();
    __builtin_amdgcn_sched_barrier(0);
    mfma_chunk(sm.s.As[2], sm.s.Bs[0]); // t=20
  }
  __syncthreads();   // all staging reads done before aliased LDS overlay

  // ---------------- fused GEMM2: silu(acc+b1) @ W2t[e], K = 128 ----------------
  const u16* w2k = W2t + (size_t)e * HID * HID;
  // prefetch BOTH W2 chunks under the As2-write phase
  #pragma unroll
  for (int kc = 0; kc < 2; ++kc)
    #pragma unroll
    for (int i = 0; i < 4; ++i) {
      int rbase = (wave * 4 + i) * 8;
      async16(w2k + (size_t)(rbase + rloc) * HID + kc * 64 + gsrc * 8,
              &sm.g.Bs2[kc][rbase * 64]);
    }

  // p-gate into registers (L2-hot; hidden behind GEMM2)
  float pr[4][4];
  #pragma unroll
  for (int m = 0; m < 4; ++m)
    #pragma unroll
    for (int r = 0; r < 4; ++r)
      pr[m][r] = p_hat[(size_t)(m0 + wm * 64 + m * 16 + q * 4 + r) * KEXP + e];

  // Write the full 128x128 H1 tile as bf16 into As2, XOR-swizzled:
  // element (row,h) at As2[row*128 + ((h>>3)^(row&7))*8 + (h&7)]
  #pragma unroll
  for (int n = 0; n < 4; ++n) {
    int cl = wn * 64 + n * 16 + ln;            // h = 0..127
    float bv = b1[e * HID + cl];
    #pragma unroll
    for (int m = 0; m < 4; ++m)
      #pragma unroll
      for (int r = 0; r < 4; ++r) {
        int row = wm * 64 + m * 16 + q * 4 + r;
        sm.g.As2[row * 128 + (((cl >> 3) ^ (row & 7)) << 3) + (cl & 7)] =
            f2bf(silu(acc[m][n][r] + bv));
      }
  }

  f32x4 acc2[4][4];
  #pragma unroll
  for (int m = 0; m < 4; ++m)
    #pragma unroll
    for (int n = 0; n < 4; ++n) acc2[m][n] = fz;

  __syncthreads();   // As2 ds_writes visible + both Bs2 DMAs landed (full drain)

  #pragma unroll
  for (int kc = 0; kc < 2; ++kc) {
    #pragma unroll
    for (int ks = 0; ks < 2; ++ks) {
      short8 a[4], b[4];
      #pragma unroll
      for (int m = 0; m < 4; ++m) {
        int r = wm * 64 + m * 16 + ln;
        int G = kc * 8 + ks * 4 + q;           // 4-bit h-group
        int g = (G & 8) | ((G ^ (r & 7)) & 7);
        a[m] = *(const short8*)(&sm.g.As2[r * 128 + g * 8]);
      }
      #pragma unroll
      for (int n = 0; n < 4; ++n) {
        int c = wn * 64 + n * 16 + ln;
        int g = (ks * 4 + q) ^ (c & 7);
        b[n] = *(const short8*)(&sm.g.Bs2[kc][c * 64 + g * 8]);
      }
      #pragma unroll
      for (int m = 0; m < 4; ++m)
        #pragma unroll
        for (int n = 0; n < 4; ++n)
          acc2[m][n] = __builtin_amdgcn_mfma_f32_16x16x32_bf16(a[m], b[n], acc2[m][n], 0, 0, 0);
    }
  }
  __syncthreads();

  // ---------------- epilogue: p * silu(acc2 + b2) -> bf16 H, coalesced ----------------
  u16* hb = H + (size_t)m0 * NTOT + e * HID;
  #pragma unroll 1
  for (int hf = 0; hf < 2; ++hf) {
    if (wn == hf) {
      #pragma unroll
      for (int n = 0; n < 4; ++n) {
        int cl = n * 16 + ln;
        float bv = b2[e * HID + hf * 64 + cl];
        #pragma unroll
        for (int m = 0; m < 4; ++m)
          #pragma unroll
          for (int r = 0; r < 4; ++r) {
            int row = wm * 64 + m * 16 + q * 4 + r;
            sm.Cs[row * 72 + cl] = f2bf(pr[m][r] * silu(acc2[m][n][r] + bv));
          }
      }
    }
    __syncthreads();
    #pragma unroll
    for (int i = 0; i < 4; ++i) {
      int lin = tid + i * 256;
      int row = lin >> 3;
      int grp = lin & 7;
      *(u32x4*)(hb + (size_t)row * NTOT + hf * 64 + grp * 8) =
          *(const u32x4*)(&sm.Cs[row * 72 + grp * 8]);
    }
    __syncthreads();
  }
#undef H1_SA
#undef H1_SB
#undef H1_CH
}

// ---------------------------------------------------------------------------
// out_gemm: out = Hg @ W3t2^T + (p @ b3). M=32768 N=256 K=1024 = 16 chunks.
// REBUILT as a clone of h1's verified GEMM1 pipeline: 128x128 tile, 4x4 wave
// tile (2x MFMA density, 0.5 KB/MFMA LDS), As[3] depth-2 (H = HBM stream),
// Bs[2] depth-1 (W3t2 = 0.5 MB, L2-resident), steady vmcnt(4).
// 512 blocks = exactly 2/CU x 256 CU.  80 KB LDS -> 2 blk/CU.
// p_hat/b3 read directly in epilogue (L2-hot, once) — no Ps/B3s LDS.
// ---------------------------------------------------------------------------
__global__ __launch_bounds__(256, 2)
void out_gemm(const u16* __restrict__ H, const float* __restrict__ p_hat,
              const u16* __restrict__ W3t2, const float* __restrict__ b3,
              float* __restrict__ out) {
  __shared__ struct {
    u16 As[3][8192];   // 48 KB (128 x 64 each)
    u16 Bs[2][8192];   // 32 KB (128 x 64 each)
  } sm;

  const int tid  = threadIdx.x;
  const int wave = tid >> 6;
  const int lane = tid & 63;
  const int q    = lane >> 4;
  const int ln   = lane & 15;
  const int wm   = wave >> 1, wn = wave & 1;
  const int bid  = blockIdx.x;
  const int mt   = ((bid >> 4) << 3) | (bid & 7);   // 0..255; bn-siblings same XCD
  const int bn   = (bid >> 3) & 1;
  const int m0   = mt * 128, n0 = bn * 128;
  const u16* hb  = H + (size_t)m0 * NTOT;
  const u16* w3b = W3t2 + (size_t)n0 * NTOT;

  const f32x4 fz = {0.f, 0.f, 0.f, 0.f};
  f32x4 acc[4][4];
  #pragma unroll
  for (int m = 0; m < 4; ++m)
    #pragma unroll
    for (int n = 0; n < 4; ++n) acc[m][n] = fz;

  const int rloc = lane >> 3;
  const int gsw  = lane & 7;
  const int gsrc = gsw ^ rloc;

#define OG_SA(d0, buf) { \
  _Pragma("unroll") \
  for (int i_ = 0; i_ < 4; ++i_) { \
    int rb_ = (wave * 4 + i_) * 8; \
    async16(hb + (size_t)(rb_ + rloc) * NTOT + (d0) + gsrc * 8, &sm.As[buf][rb_ * 64]); \
  } }
#define OG_SB(d0, buf) { \
  _Pragma("unroll") \
  for (int i_ = 0; i_ < 4; ++i_) { \
    int rb_ = (wave * 4 + i_) * 8; \
    async16(w3b + (size_t)(rb_ + rloc) * NTOT + (d0) + gsrc * 8, &sm.Bs[buf][rb_ * 64]); \
  } }

  auto mfma_chunk = [&](const u16* Ab, const u16* Bb) {
    __builtin_amdgcn_s_setprio(1);
    #pragma unroll
    for (int ks = 0; ks < 2; ++ks) {
      short8 a[4], b[4];
      #pragma unroll
      for (int m = 0; m < 4; ++m) {
        int r = wm * 64 + m * 16 + ln;
        int g = (ks * 4 + q) ^ (r & 7);
        a[m] = *(const short8*)(&Ab[r * 64 + g * 8]);
      }
      #pragma unroll
      for (int n = 0; n < 4; ++n) {
        int c = wn * 64 + n * 16 + ln;
        int g = (ks * 4 + q) ^ (c & 7);
        b[n] = *(const short8*)(&Bb[c * 64 + g * 8]);
      }
      #pragma unroll
      for (int m = 0; m < 4; ++m)
        #pragma unroll
        for (int n = 0; n < 4; ++n)
          acc[m][n] = __builtin_amdgcn_mfma_f32_16x16x32_bf16(a[m], b[n], acc[m][n], 0, 0, 0);
    }
    __builtin_amdgcn_s_setprio(0);
  };

#define OG_CH(trel, ac, bc, bp, ap, vm) \
  OG_SB(db + ((trel) + 1) * 64, bp); \
  OG_SA(db + ((trel) + 2) * 64, ap); \
  mfma_chunk(sm.As[ac], sm.Bs[bc]); \
  asm volatile("s_waitcnt vmcnt(" #vm ")" ::: "memory"); \
  __builtin_amdgcn_s_barrier(); \
  __builtin_amdgcn_sched_barrier(0);

  // prologue: A0->a0, B0->b0, A1->a1; wait A0,B0 (A1 in flight)
  OG_SA(0, 0); OG_SB(0, 0); OG_SA(64, 1);
  asm volatile("s_waitcnt vmcnt(4)" ::: "memory");
  __builtin_amdgcn_s_barrier();
  __builtin_amdgcn_sched_barrier(0);

  // t = 0..11: a = t%3, b = t%2, 6-chunk pattern x2
  #pragma unroll 1
  for (int j = 0; j < 2; ++j) {
    const int db = j * 384;
    OG_CH(0, 0, 0, 1, 2, 4)
    OG_CH(1, 1, 1, 0, 0, 4)
    OG_CH(2, 2, 0, 1, 1, 4)
    OG_CH(3, 0, 1, 0, 2, 4)
    OG_CH(4, 1, 0, 1, 0, 4)
    OG_CH(5, 2, 1, 0, 1, 4)
  }
  // tail: t = 12..15 (12%3=0,12%2=0 — same phase as the macro start)
  {
    const int db = 768;
    OG_CH(0, 0, 0, 1, 2, 4)            // t=12: B(13)->b1, A(14)->a2
    OG_CH(1, 1, 1, 0, 0, 4)            // t=13: B(14)->b0, A(15)->a0
    OG_SB(db + 192, 1);                // t=14: B(15)->b1 only
    mfma_chunk(sm.As[2], sm.Bs[0]);
    asm volatile("s_waitcnt vmcnt(0)" ::: "memory");
    __builtin_amdgcn_s_barrier();
    __builtin_amdgcn_sched_barrier(0);
    mfma_chunk(sm.As[0], sm.Bs[1]);    // t=15
  }

  // ---- epilogue: out = acc + sum_k p[row][k]*b3[k][col], fp32 direct ----
  // b3 columns for this thread's 4 n-slots (b3 is 4 KB, L2-hot)
  float b3c[4][8];
  #pragma unroll
  for (int n = 0; n < 4; ++n) {
    int gcol = n0 + wn * 64 + n * 16 + ln;
    #pragma unroll
    for (int k = 0; k < 8; ++k) b3c[n][k] = b3[k * LATENT + gcol];
  }
  #pragma unroll
  for (int m = 0; m < 4; ++m)
    #pragma unroll
    for (int r = 0; r < 4; ++r) {
      int grow = m0 + wm * 64 + m * 16 + q * 4 + r;
      float4 p0 = *(const float4*)(p_hat + (size_t)grow * KEXP);
      float4 p1 = *(const float4*)(p_hat + (size_t)grow * KEXP + 4);
      #pragma unroll
      for (int n = 0; n < 4; ++n) {
        int gcol = n0 + wn * 64 + n * 16 + ln;
        float v = acc[m][n][r]
                + p0.x * b3c[n][0] + p0.y * b3c[n][1] + p0.z * b3c[n][2] + p0.w * b3c[n][3]
                + p1.x * b3c[n][4] + p1.y * b3c[n][5] + p1.z * b3c[n][6] + p1.w * b3c[n][7];
        out[(size_t)grow * LATENT + gcol] = v;
      }
    }
#undef OG_SA
#undef OG_SB
#undef OG_CH
}

// ---------------------------------------------------------------------------
// FALLBACK PATH (only if ws_size too small for Xbf): previous-session
// h1_gemm + h2_gemm, verbatim.
// ---------------------------------------------------------------------------
__global__ __launch_bounds__(256, 4)
void h1_gemm(const float* __restrict__ cond, const float* __restrict__ uu,
             const float* __restrict__ tau, const u16* __restrict__ W1t,
             const float* __restrict__ b1, u16* __restrict__ H1) {
  __shared__ union {
    struct { u16 As[128 * 64]; u16 Bs[128 * 64]; } s;
    u16 Cs[128 * 72];
  } sm;

  const int tid  = threadIdx.x;
  const int wave = tid >> 6;
  const int lane = tid & 63;
  const int q    = lane >> 4;
  const int ln   = lane & 15;
  const int wm   = wave >> 1, wn = wave & 1;
  const int bid  = blockIdx.x;
  const int mt   = ((bid >> 6) << 3) | (bid & 7);
  const int e    = (bid >> 3) & 7;
  const int m0   = mt * 128, n0 = e * 128;
  const u16* w1k = W1t + (size_t)e * HID * EINP;

  const f32x4 fz = {0.f, 0.f, 0.f, 0.f};
  f32x4 acc[4][4];
  #pragma unroll
  for (int m = 0; m < 4; ++m)
    #pragma unroll
    for (int n = 0; n < 4; ++n) acc[m][n] = fz;

  #pragma unroll 1
  for (int ic = 0; ic < NCH; ++ic) {
    const int d0 = ic * 64;
    #pragma unroll
    for (int i = 0; i < 4; ++i) {
      int lin  = tid + i * 256;
      int row  = lin >> 3;
      int gsw  = lin & 7;
      int gsrc = gsw ^ (row & 7);
      int gr   = m0 + row;
      float f0, f1, f2, f3, f4, f5, f6, f7;
      if (d0 < 256) {
        const float4* p = (const float4*)(uu + (size_t)gr * LATENT + d0 + gsrc * 8);
        float4 A = p[0], Bv = p[1];
        f0 = A.x; f1 = A.y; f2 = A.z; f3 = A.w; f4 = Bv.x; f5 = Bv.y; f6 = Bv.z; f7 = Bv.w;
      } else if (d0 < 1280) {
        const float4* p = (const float4*)(cond + (size_t)gr * CONDD + (d0 - 256) + gsrc * 8);
        float4 A = p[0], Bv = p[1];
        f0 = A.x; f1 = A.y; f2 = A.z; f3 = A.w; f4 = Bv.x; f5 = Bv.y; f6 = Bv.z; f7 = Bv.w;
      } else {
        float tv = tau[gr];
        f0 = (gsrc == 0) ? tv : 0.f;
        f1 = f2 = f3 = f4 = f5 = f6 = f7 = 0.f;
      }
      u32x4 pk;
      pk[0] = (uint32_t)f2bf(f0) | ((uint32_t)f2bf(f1) << 16);
      pk[1] = (uint32_t)f2bf(f2) | ((uint32_t)f2bf(f3) << 16);
      pk[2] = (uint32_t)f2bf(f4) | ((uint32_t)f2bf(f5) << 16);
      pk[3] = (uint32_t)f2bf(f6) | ((uint32_t)f2bf(f7) << 16);
      *(u32x4*)(&sm.s.As[row * 64 + gsw * 8]) = pk;
    }
    {
      int rloc = lane >> 3;
      int gsw  = lane & 7;
      int gsrc = gsw ^ rloc;
      #pragma unroll
      for (int i = 0; i < 4; ++i) {
        int rbase = (wave * 4 + i) * 8;
        async16(w1k + (size_t)(rbase + rloc) * EINP + d0 + gsrc * 8,
                &sm.s.Bs[rbase * 64]);
      }
    }
    __syncthreads();
    #pragma unroll
    for (int ks = 0; ks < 2; ++ks) {
      short8 a[4], b[4];
      #pragma unroll
      for (int m = 0; m < 4; ++m) {
        int r = wm * 64 + m * 16 + ln;
        int g = (ks * 4 + q) ^ (r & 7);
        a[m] = *(const short8*)(&sm.s.As[r * 64 + g * 8]);
      }
      #pragma unroll
      for (int n = 0; n < 4; ++n) {
        int c = wn * 64 + n * 16 + ln;
        int g = (ks * 4 + q) ^ (c & 7);
        b[n] = *(const short8*)(&sm.s.Bs[c * 64 + g * 8]);
      }
      #pragma unroll
      for (int m = 0; m < 4; ++m)
        #pragma unroll
        for (int n = 0; n < 4; ++n)
          acc[m][n] = __builtin_amdgcn_mfma_f32_16x16x32_bf16(a[m], b[n], acc[m][n], 0, 0, 0);
    }
    __syncthreads();
  }

  #pragma unroll 1
  for (int hf = 0; hf < 2; ++hf) {
    if (wn == hf) {
      #pragma unroll
      for (int n = 0; n < 4; ++n) {
        int cl = n * 16 + ln;
        float bv = b1[n0 + hf * 64 + cl];
        #pragma unroll
        for (int m = 0; m < 4; ++m)
          #pragma unroll
          for (int r = 0; r < 4; ++r)
            sm.Cs[(wm * 64 + m * 16 + q * 4 + r) * 72 + cl] = f2bf(silu(acc[m][n][r] + bv));
      }
    }
    __syncthreads();
    #pragma unroll
    for (int i = 0; i < 4; ++i) {
      int lin = tid + i * 256;
      int row = lin >> 3;
      int grp = lin & 7;
      *(u32x4*)(H1 + (size_t)(m0 + row) * NTOT + n0 + hf * 64 + grp * 8) =
          *(const u32x4*)(&sm.Cs[row * 72 + grp * 8]);
    }
    __syncthreads();
  }
}

__global__ __launch_bounds__(256, 4)
void h2_gemm(u16* __restrict__ H, const float* __restrict__ p_hat,
             const u16* __restrict__ W2t, const float* __restrict__ b2) {
  __shared__ struct {
    union { struct { u16 As[128 * 64]; u16 Bs[128 * 64]; } s; u16 Cs[128 * 72]; } u;
    float Ps[128];
  } sm;

  const int tid  = threadIdx.x;
  const int wave = tid >> 6;
  const int lane = tid & 63;
  const int q    = lane >> 4;
  const int ln   = lane & 15;
  const int wm   = wave >> 1, wn = wave & 1;
  const int mt   = blockIdx.x >> 3;
  const int e    = blockIdx.x & 7;
  const int row0 = mt * 128;

  if (tid < 128) sm.Ps[tid] = p_hat[(size_t)(row0 + tid) * KEXP + e];

  const u16* w2k = W2t + (size_t)e * HID * HID;
  u16* hb = H + (size_t)row0 * NTOT + e * HID;

  const f32x4 fz = {0.f, 0.f, 0.f, 0.f};
  f32x4 acc[4][4];
  #pragma unroll
  for (int m = 0; m < 4; ++m)
    #pragma unroll
    for (int n = 0; n < 4; ++n) acc[m][n] = fz;

  const int rloc = lane >> 3;
  const int gsw  = lane & 7;
  const int gsrc = gsw ^ rloc;

  #pragma unroll 1
  for (int kc = 0; kc < 2; ++kc) {
    #pragma unroll
    for (int i = 0; i < 4; ++i) {
      int rbase = (wave * 4 + i) * 8;
      async16(hb + (size_t)(rbase + rloc) * NTOT + kc * 64 + gsrc * 8,
              &sm.u.s.As[rbase * 64]);
      async16(w2k + (size_t)(rbase + rloc) * HID + kc * 64 + gsrc * 8,
              &sm.u.s.Bs[rbase * 64]);
    }
    __syncthreads();
    #pragma unroll
    for (int ks = 0; ks < 2; ++ks) {
      short8 a[4], b[4];
      #pragma unroll
      for (int m = 0; m < 4; ++m) {
        int r = wm * 64 + m * 16 + ln;
        int g = (ks * 4 + q) ^ (r & 7);
        a[m] = *(const short8*)(&sm.u.s.As[r * 64 + g * 8]);
      }
      #pragma unroll
      for (int n = 0; n < 4; ++n) {
        int c = wn * 64 + n * 16 + ln;
        int g = (ks * 4 + q) ^ (c & 7);
        b[n] = *(const short8*)(&sm.u.s.Bs[c * 64 + g * 8]);
      }
      #pragma unroll
      for (int m = 0; m < 4; ++m)
        #pragma unroll
        for (int n = 0; n < 4; ++n)
          acc[m][n] = __builtin_amdgcn_mfma_f32_16x16x32_bf16(a[m], b[n], acc[m][n], 0, 0, 0);
    }
    __syncthreads();
  }

  #pragma unroll 1
  for (int hf = 0; hf < 2; ++hf) {
    if (wn == hf) {
      #pragma unroll
      for (int n = 0; n < 4; ++n) {
        int cl = n * 16 + ln;
        float bv = b2[e * HID + hf * 64 + cl];
        #pragma unroll
        for (int m = 0; m < 4; ++m)
          #pragma unroll
          for (int r = 0; r < 4; ++r) {
            int row = wm * 64 + m * 16 + q * 4 + r;
            sm.u.Cs[row * 72 + cl] = f2bf(sm.Ps[row] * silu(acc[m][n][r] + bv));
          }
      }
    }
    __syncthreads();
    #pragma unroll
    for (int i = 0; i < 4; ++i) {
      int lin = tid + i * 256;
      int row = lin >> 3;
      int grp = lin & 7;
      *(u32x4*)(hb + (size_t)row * NTOT + hf * 64 + grp * 8) =
          *(const u32x4*)(&sm.u.Cs[row * 72 + grp * 8]);
    }
    __syncthreads();
  }
}

extern "C" void kernel_launch(void* const* d_in, const int* in_sizes, int n_in,
                              void* d_out, int out_size, void* d_ws, size_t ws_size,
                              hipStream_t stream) {
  const float* cond  = (const float*)d_in[0];
  const float* u     = (const float*)d_in[1];
  const float* tau   = (const float*)d_in[2];
  const float* p_hat = (const float*)d_in[3];
  const float* W1    = (const float*)d_in[4];
  const float* b1    = (const float*)d_in[5];
  const float* W2    = (const float*)d_in[6];
  const float* b2    = (const float*)d_in[7];
  const float* W3    = (const float*)d_in[8];
  const float* b3    = (const float*)d_in[9];
  float* out = (float*)d_out;

  const size_t N1 = (size_t)KEXP * HID * EINP;    // 1,376,256
  const size_t N2 = (size_t)KEXP * HID * HID;     //   131,072
  const size_t N3 = (size_t)LATENT * NTOT;        //   262,144
  const size_t NH = (size_t)BROWS * NTOT;         // 33,554,432
  const size_t NX = (size_t)BROWS * EINP;         // 44,040,192 (bf16 X)

  u16* W1t  = (u16*)d_ws;
  u16* W2t  = W1t + N1;
  u16* W3t2 = W2t + N2;
  u16* H    = W3t2 + N3;

  if (ws_size >= (N1 + N2 + N3 + NH + NX) * sizeof(u16)) {
    // ---- fast path: merged prep + deep-pipelined fused h1+h2 + 128x128 out ----
    u16* Xbf = H + NH;
    prep<<<WCONV_TILES + XBLK, 256, 0, stream>>>(W1, W2, W3, cond, u, tau,
                                                 W1t, W2t, W3t2, Xbf);
    h1_fused<<<2048, 256, 0, stream>>>(Xbf, W1t, b1, W2t, b2, p_hat, H);
    out_gemm<<<512, 256, 0, stream>>>(H, p_hat, W3t2, b3, out);
  } else if (ws_size >= (N1 + N2 + N3 + NH) * sizeof(u16)) {
    // ---- fallback: previous-session path ----
    prep<<<WCONV_TILES, 256, 0, stream>>>(W1, W2, W3, cond, u, tau,
                                          W1t, W2t, W3t2, (u16*)nullptr);
    h1_gemm<<<2048, 256, 0, stream>>>(cond, u, tau, W1t, b1, H);
    h2_gemm<<<2048, 256, 0, stream>>>(H, p_hat, W2t, b2);
    out_gemm<<<512, 256, 0, stream>>>(H, p_hat, W3t2, b3, out);
  }
}